// Round 17
// baseline (764.707 us; speedup 1.0000x reference)
//
#include <hip/hip_runtime.h>
#include <hip/hip_bf16.h>
#include <cstddef>

// ---------------------------------------------------------------------------
// EncoderModule: 5x causal conv1d (K=7) + ELU, then 2x VQ argmin (1024 codes, D=64)
// B=64, L=48000, strides 2,2,2,3,1; channels 1->16->32->64->64->128
// Output: int32 indices, shape (2, 64, 2000)
//
// Inter-layer tensors: fp32, t-major [t][ci]. Convs 1-4: 6-term split3-bf16
// MFMA (round-14 numerics, passed absmax 0).
// VQ: codebook pre-scaled by -2, ||c||^2 folded into MFMA accumulator init,
// med3 best/second; LDS z-frag/B-chunk buffers UNIONED (32KB -> 4 blocks/CU),
// next chunk register-prefetched; launch_bounds(256,4) so the prefetch regs
// stay in VGPRs (r16 lesson: default bounds -> 64-VGPR target -> scratch
// spill -> 457MB WRITE_SIZE). gap < 0.04 -> flag; paired exact rescore.
// ---------------------------------------------------------------------------

using bf16x8 = __attribute__((ext_vector_type(8))) short;
using s16x4  = __attribute__((ext_vector_type(4))) short;
using f32x4  = __attribute__((ext_vector_type(4))) float;

static __device__ __forceinline__ short f2bf(float f) {
    __hip_bfloat16 h = __float2bfloat16(f);   // RNE
    union { __hip_bfloat16 h; short s; } u; u.h = h;
    return u.s;
}
static __device__ __forceinline__ float bf2f(short s) {
    union { unsigned u; float f; } v;
    v.u = ((unsigned)(unsigned short)s) << 16;
    return v.f;
}
static __device__ __forceinline__ void split3(float v, short& s0, short& s1, short& s2) {
    s0 = f2bf(v);  float r1 = v  - bf2f(s0);   // exact
    s1 = f2bf(r1); float r2 = r1 - bf2f(s1);   // exact
    s2 = f2bf(r2);                             // residual ~2^-24 |v|
}
static __device__ __forceinline__ float elu(float v) {
    return v > 0.0f ? v : expm1f(v);
}

// ---------------- conv0: fp32 VALU, t-major phase-split store ---------------
__global__ __launch_bounds__(256) void conv0_kernel(
    const float* __restrict__ x, const float* __restrict__ w,
    const float* __restrict__ bias, float* __restrict__ H0)
{
    __shared__ float xs[261];                  // (128-1)*2+7
    int tb = blockIdx.x, b = blockIdx.y;
    int t0 = tb * 128;
    int tid = threadIdx.x, lane = tid & 63;
    int wv = __builtin_amdgcn_readfirstlane(tid >> 6);

    const float* xb = x + (size_t)b * 48000;
    int g0 = t0 * 2 - 6;
    for (int i = tid; i < 261; i += 256) {
        int gx = g0 + i;
        xs[i] = (gx >= 0 && gx < 48000) ? xb[gx] : 0.0f;
    }
    __syncthreads();

    int co0 = wv * 4;
    float acc[4][2];
    #pragma unroll
    for (int c = 0; c < 4; ++c) { acc[c][0] = 0.f; acc[c][1] = 0.f; }

    float xw[2][7];
    #pragma unroll
    for (int u = 0; u < 2; ++u)
        #pragma unroll
        for (int k = 0; k < 7; ++k)
            xw[u][k] = xs[(lane + 64 * u) * 2 + k];
    #pragma unroll
    for (int c = 0; c < 4; ++c) {
        const float* wp = w + (size_t)(co0 + c) * 7;   // s_load
        #pragma unroll
        for (int k = 0; k < 7; ++k) {
            float wk = wp[k];
            acc[c][0] = fmaf(wk, xw[0][k], acc[c][0]);
            acc[c][1] = fmaf(wk, xw[1][k], acc[c][1]);
        }
    }

    #pragma unroll
    for (int u = 0; u < 2; ++u) {
        int t = t0 + lane + 64 * u;
        if (t < 24000) {
            float4 vv;
            vv.x = elu(acc[0][u] + bias[co0 + 0]);
            vv.y = elu(acc[1][u] + bias[co0 + 1]);
            vv.z = elu(acc[2][u] + bias[co0 + 2]);
            vv.w = elu(acc[3][u] + bias[co0 + 3]);
            *(float4*)(H0 + ((size_t)b * 12000 + (t >> 1)) * 32 + (t & 1) * 16 + co0) = vv;
        }
    }
}

// ---------------- weight prep: 3-level bf16 A-fragments ---------------------
template<int CIN, int COUT, int TAPS>
__global__ void wprep3_kernel(const float* __restrict__ w, short* __restrict__ frag)
{
    constexpr int KC = CIN / 32;
    int co = threadIdx.x;
    if (co >= COUT) return;
    int mt = co >> 4, nc = co & 15;
    for (int kc = 0; kc < KC; ++kc)
        for (int k = 0; k < TAPS; ++k)
            #pragma unroll
            for (int lh = 0; lh < 4; ++lh) {
                bf16x8 p0, p1, p2;
                #pragma unroll
                for (int j = 0; j < 8; ++j) {
                    int ci = kc * 32 + lh * 8 + j;
                    float f = w[(size_t)co * CIN * 7 + ci * 7 + k];
                    short a, bb, c; split3(f, a, bb, c);
                    p0[j] = a; p1[j] = bb; p2[j] = c;
                }
                size_t base = ((size_t)(mt * KC + kc) * TAPS + k) * 3;
                int off = (lh * 16 + nc) * 8;
                *(bf16x8*)(frag + (base + 0) * 512 + off) = p0;
                *(bf16x8*)(frag + (base + 1) * 512 + off) = p1;
                *(bf16x8*)(frag + (base + 2) * 512 + off) = p2;
            }
}

// phase-split packing (stride-2 K=7 -> stride-1 K=4 over doubled channels)
template<int CINH, int COUT>
__global__ void wprep3_ps_kernel(const float* __restrict__ w, short* __restrict__ frag)
{
    constexpr int CIN = 2 * CINH;
    constexpr int KC  = CIN / 32;
    int co = threadIdx.x;
    if (co >= COUT) return;
    int mt = co >> 4, nc = co & 15;
    for (int kc = 0; kc < KC; ++kc)
        for (int m = 0; m < 4; ++m)
            #pragma unroll
            for (int lh = 0; lh < 4; ++lh) {
                bf16x8 p0, p1, p2;
                #pragma unroll
                for (int j = 0; j < 8; ++j) {
                    int cp = kc * 32 + lh * 8 + j;
                    float f;
                    if (cp < CINH)  f = w[(size_t)co * CINH * 7 + cp * 7 + 2 * m];
                    else if (m < 3) f = w[(size_t)co * CINH * 7 + (cp - CINH) * 7 + 2 * m + 1];
                    else            f = 0.0f;
                    short a, bb, c; split3(f, a, bb, c);
                    p0[j] = a; p1[j] = bb; p2[j] = c;
                }
                size_t base = ((size_t)(mt * KC + kc) * 4 + m) * 3;
                int off = (lh * 16 + nc) * 8;
                *(bf16x8*)(frag + (base + 0) * 512 + off) = p0;
                *(bf16x8*)(frag + (base + 1) * 512 + off) = p1;
                *(bf16x8*)(frag + (base + 2) * 512 + off) = p2;
            }
}

// ---------------- conv via 6-term split3-bf16 MFMA, t-major fp32 I/O --------
template<int S, int CIN, int COUT, int NTL, int TAPS, int PAD, int OUTMODE>
__global__ __launch_bounds__(256) void conv_mfma3_kernel(
    const float* __restrict__ Hin, const short* __restrict__ wfrag,
    const float* __restrict__ bias, float* __restrict__ Hout,
    int Lin, int Lout)
{
    constexpr int KC   = CIN / 32;
    constexpr int MT   = COUT / 16;
    constexpr int NT   = NTL * 64;
    constexpr int ROWS = (NT - 1) * S + TAPS;
    constexpr int ROWB = CIN * 2;
    constexpr int NSL  = CIN / 4;
    __shared__ __align__(16) short pl0[ROWS * CIN];
    __shared__ __align__(16) short pl1[ROWS * CIN];
    __shared__ __align__(16) short pl2[ROWS * CIN];

    int nb = blockIdx.x, b = blockIdx.y;
    int t0 = nb * NT;
    int tid = threadIdx.x, lane = tid & 63, wv = tid >> 6;
    int g0 = t0 * S - PAD;

    const float* inb = Hin + (size_t)b * Lin * CIN;
    for (int e = tid; e < ROWS * NSL; e += 256) {
        int rr = e / NSL, sl = e % NSL;
        int g = g0 + rr;
        float4 v = {0.f, 0.f, 0.f, 0.f};
        if (g >= 0 && g < Lin)
            v = *(const float4*)(inb + (size_t)g * CIN + sl * 4);
        int xr = (CIN == 64) ? (rr & 7) : ((rr >> 1) & 3);
        int byte = rr * ROWB + ((((sl >> 1) ^ xr) << 4) | ((sl & 1) << 3));
        s16x4 q0, q1, q2;
        short a0, a1, a2;
        split3(v.x, a0, a1, a2); q0[0] = a0; q1[0] = a1; q2[0] = a2;
        split3(v.y, a0, a1, a2); q0[1] = a0; q1[1] = a1; q2[1] = a2;
        split3(v.z, a0, a1, a2); q0[2] = a0; q1[2] = a1; q2[2] = a2;
        split3(v.w, a0, a1, a2); q0[3] = a0; q1[3] = a1; q2[3] = a2;
        *(s16x4*)((char*)pl0 + byte) = q0;
        *(s16x4*)((char*)pl1 + byte) = q1;
        *(s16x4*)((char*)pl2 + byte) = q2;
    }
    __syncthreads();

    f32x4 acc[NTL][MT];
    #pragma unroll
    for (int n = 0; n < NTL; ++n)
        #pragma unroll
        for (int m = 0; m < MT; ++m) acc[n][m] = (f32x4){0.f, 0.f, 0.f, 0.f};

    int ncol = lane & 15, nq = lane >> 4;

    for (int k = 0; k < TAPS; ++k) {
        #pragma unroll
        for (int kc = 0; kc < KC; ++kc) {
            int colb = (kc * 32 + nq * 8) * 2;
            bf16x8 B0[NTL], B1[NTL], B2[NTL];
            #pragma unroll
            for (int ntl = 0; ntl < NTL; ++ntl) {
                int r  = S * ((wv * NTL + ntl) * 16 + ncol) + k;
                int xr = (CIN == 64) ? (r & 7) : ((r >> 1) & 3);
                int byte = r * ROWB + (colb ^ (xr << 4));
                B0[ntl] = *(const bf16x8*)((char*)pl0 + byte);
                B1[ntl] = *(const bf16x8*)((char*)pl1 + byte);
                B2[ntl] = *(const bf16x8*)((char*)pl2 + byte);
            }
            #pragma unroll
            for (int m = 0; m < MT; ++m) {
                size_t base = ((size_t)(m * KC + kc) * TAPS + k) * 3;
                bf16x8 a0 = *(const bf16x8*)(wfrag + (base + 0) * 512 + lane * 8);
                bf16x8 a1 = *(const bf16x8*)(wfrag + (base + 1) * 512 + lane * 8);
                bf16x8 a2 = *(const bf16x8*)(wfrag + (base + 2) * 512 + lane * 8);
                #pragma unroll
                for (int ntl = 0; ntl < NTL; ++ntl) {
                    f32x4 a = acc[ntl][m];
                    a = __builtin_amdgcn_mfma_f32_16x16x32_bf16(a0, B0[ntl], a, 0, 0, 0);
                    a = __builtin_amdgcn_mfma_f32_16x16x32_bf16(a1, B0[ntl], a, 0, 0, 0);
                    a = __builtin_amdgcn_mfma_f32_16x16x32_bf16(a2, B0[ntl], a, 0, 0, 0);
                    a = __builtin_amdgcn_mfma_f32_16x16x32_bf16(a0, B1[ntl], a, 0, 0, 0);
                    a = __builtin_amdgcn_mfma_f32_16x16x32_bf16(a1, B1[ntl], a, 0, 0, 0);
                    a = __builtin_amdgcn_mfma_f32_16x16x32_bf16(a0, B2[ntl], a, 0, 0, 0);
                    acc[ntl][m] = a;
                }
            }
        }
    }

    #pragma unroll
    for (int ntl = 0; ntl < NTL; ++ntl) {
        int n = t0 + (wv * NTL + ntl) * 16 + ncol;
        if (n < Lout) {
            #pragma unroll
            for (int m = 0; m < MT; ++m) {
                int co0 = m * 16 + nq * 4;
                float4 bb = *(const float4*)(bias + co0);
                float4 vv;
                vv.x = elu(acc[ntl][m][0] + bb.x);
                vv.y = elu(acc[ntl][m][1] + bb.y);
                vv.z = elu(acc[ntl][m][2] + bb.z);
                vv.w = elu(acc[ntl][m][3] + bb.w);
                if constexpr (OUTMODE == 0) {
                    *(float4*)(Hout + ((size_t)b * Lout + n) * COUT + co0) = vv;
                } else if constexpr (OUTMODE == 1) {
                    *(float4*)(Hout + ((size_t)b * (Lout >> 1) + (n >> 1)) * (2 * COUT)
                               + (n & 1) * COUT + co0) = vv;
                } else {
                    Hout[((size_t)b * COUT + co0 + 0) * Lout + n] = vv.x;
                    Hout[((size_t)b * COUT + co0 + 1) * Lout + n] = vv.y;
                    Hout[((size_t)b * COUT + co0 + 2) * Lout + n] = vv.z;
                    Hout[((size_t)b * COUT + co0 + 3) * Lout + n] = vv.w;
                }
            }
        }
    }
}

// ---------------- VQ prep: cc (fp32, +||c||^2) + (-2c) hi/lo bf16 B-frags ---
__global__ __launch_bounds__(256) void vq_prep_kernel(
    const float* __restrict__ cbs, float* __restrict__ cc, short* __restrict__ cbf)
{
    int c = blockIdx.x * 256 + threadIdx.x;   // 0..2047
    if (c >= 2048) return;
    int cb = c >> 10, nl = c & 1023;
    const float* row = cbs + (size_t)c * 64;
    float v[64];
    float s = 0.f;
    #pragma unroll
    for (int i = 0; i < 16; ++i) {
        float4 q = ((const float4*)row)[i];
        v[4*i+0] = q.x; v[4*i+1] = q.y; v[4*i+2] = q.z; v[4*i+3] = q.w;
        s += q.x*q.x + q.y*q.y + q.z*q.z + q.w*q.w;
    }
    cc[c] = s;
    int nt = nl >> 4, nc = nl & 15;
    #pragma unroll
    for (int kc = 0; kc < 2; ++kc)
        #pragma unroll
        for (int lh = 0; lh < 4; ++lh) {
            bf16x8 ph, pl;
            #pragma unroll
            for (int j = 0; j < 8; ++j) {
                float f = -2.0f * v[kc*32 + lh*8 + j];   // exact scaling
                short h = f2bf(f);
                ph[j] = h;
                pl[j] = f2bf(f - bf2f(h));
            }
            size_t base = ((((size_t)cb*64 + nt)*2 + kc)*2);
            *(bf16x8*)(cbf + ((base + 0)*64 + (lh*16 + nc)) * 8) = ph;
            *(bf16x8*)(cbf + ((base + 1)*64 + (lh*16 + nc)) * 8) = pl;
        }
}

__global__ void zero_cnt_kernel(int* cnt) {
    if (threadIdx.x == 0 && blockIdx.x == 0) { cnt[0] = 0; cnt[1] = 0; }
}

// ---------------- VQ main: MFMA scores, unioned LDS + chunk prefetch --------
#define VQ_MARGIN 0.04f

__global__ __launch_bounds__(256, 4) void vq_mfma_kernel(
    const float* __restrict__ z, const short* __restrict__ cbf,
    const float* __restrict__ ccg, int* __restrict__ out,
    int* __restrict__ cnt, int* __restrict__ list0, int* __restrict__ list1)
{
    // 32 KB union: z A-fragments (staging phase) then B-frag chunk (main loop)
    __shared__ __align__(16) short sbuf[16384];
    short* zf0 = sbuf;            // [8 mt][2 kc][64 lane][8] hi
    short* zf1 = sbuf + 8192;     // lo
    short* cbc = sbuf;            // chunk: [8 ntl][2 kc][2 hl][64 lane][8]

    const int T = 2000;
    int mblk = blockIdx.x;
    int cb   = blockIdx.y;
    int b    = blockIdx.z;
    int t0   = mblk * 128;
    int tid  = threadIdx.x;
    int lane = tid & 63;
    int wv   = tid >> 6;
    int* list = cb ? list1 : list0;

    // ---- stage z -> hi/lo A-fragments (b128 rows, conflict-free) ----
    const float* zb = z + ((size_t)b*128 + (size_t)cb*64) * T;
    for (int e = tid; e < 128 * 8; e += 256) {
        int tl = e & 127;
        int d0 = (e >> 7) * 8;
        int tt = t0 + tl; if (tt > T - 1) tt = T - 1;
        bf16x8 hi, lo;
        #pragma unroll
        for (int jj = 0; jj < 8; ++jj) {
            float v = zb[(size_t)(d0 + jj) * T + tt];
            short h = f2bf(v);
            hi[jj] = h;
            lo[jj] = f2bf(v - bf2f(h));
        }
        int mt = tl >> 4, kc = d0 >> 5;
        int lw = ((d0 & 31) >> 3) * 16 + (tl & 15);
        int idx = ((mt*2 + kc)*64 + lw) * 8;
        *(bf16x8*)&zf0[idx] = hi;
        *(bf16x8*)&zf1[idx] = lo;
    }
    __syncthreads();

    bf16x8 ah[2][2], al[2][2];
    #pragma unroll
    for (int mtl = 0; mtl < 2; ++mtl)
        #pragma unroll
        for (int kc = 0; kc < 2; ++kc) {
            int idx = ((((wv*2+mtl)*2 + kc)*64) + lane)*8;
            ah[mtl][kc] = *(const bf16x8*)&zf0[idx];
            al[mtl][kc] = *(const bf16x8*)&zf1[idx];
        }

    float best[2][4], second[2][4]; int bidx[2][4];
    #pragma unroll
    for (int m = 0; m < 2; ++m)
        #pragma unroll
        for (int j = 0; j < 4; ++j) { best[m][j] = 3.4e38f; second[m][j] = 3.4e38f; bidx[m][j] = 0; }

    const short* cbase = cbf + (size_t)cb * (64*2*2*64*8);
    const float* ccb   = ccg + cb * 1024;
    int c15 = lane & 15;

    // prefetch chunk 0 into registers
    float4 pre[8];
    {
        const float4* src = (const float4*)cbase;
        #pragma unroll
        for (int i = 0; i < 8; ++i) pre[i] = src[tid + 256*i];
    }

    for (int ch = 0; ch < 8; ++ch) {
        __syncthreads();   // all reads of sbuf (zf regs or prev chunk) done
        {
            float4* dst = (float4*)cbc;
            #pragma unroll
            for (int i = 0; i < 8; ++i) dst[tid + 256*i] = pre[i];
        }
        __syncthreads();
        if (ch < 7) {      // prefetch next chunk (latency hidden under MFMAs)
            const float4* src = (const float4*)(cbase + (size_t)(ch + 1) * (8*2*2*64*8));
            #pragma unroll
            for (int i = 0; i < 8; ++i) pre[i] = src[tid + 256*i];
        }

        #pragma unroll
        for (int ntl = 0; ntl < 8; ++ntl) {
            bf16x8 b0h = *(const bf16x8*)&cbc[(((ntl*2 + 0)*2 + 0)*64 + lane)*8];
            bf16x8 b0l = *(const bf16x8*)&cbc[(((ntl*2 + 0)*2 + 1)*64 + lane)*8];
            bf16x8 b1h = *(const bf16x8*)&cbc[(((ntl*2 + 1)*2 + 0)*64 + lane)*8];
            bf16x8 b1l = *(const bf16x8*)&cbc[(((ntl*2 + 1)*2 + 1)*64 + lane)*8];
            int  code = ch*128 + ntl*16 + c15;
            float ccv = ccb[code];                 // L1-resident 8KB table
            #pragma unroll
            for (int mtl = 0; mtl < 2; ++mtl) {
                f32x4 p = {ccv, ccv, ccv, ccv};
                __builtin_amdgcn_s_setprio(1);
                p = __builtin_amdgcn_mfma_f32_16x16x32_bf16(ah[mtl][0], b0h, p, 0, 0, 0);
                p = __builtin_amdgcn_mfma_f32_16x16x32_bf16(al[mtl][0], b0h, p, 0, 0, 0);
                p = __builtin_amdgcn_mfma_f32_16x16x32_bf16(ah[mtl][0], b0l, p, 0, 0, 0);
                p = __builtin_amdgcn_mfma_f32_16x16x32_bf16(ah[mtl][1], b1h, p, 0, 0, 0);
                p = __builtin_amdgcn_mfma_f32_16x16x32_bf16(al[mtl][1], b1h, p, 0, 0, 0);
                p = __builtin_amdgcn_mfma_f32_16x16x32_bf16(ah[mtl][1], b1l, p, 0, 0, 0);
                __builtin_amdgcn_s_setprio(0);
                #pragma unroll
                for (int j = 0; j < 4; ++j) {
                    float s = p[j];
                    bool lt = s < best[mtl][j];
                    second[mtl][j] = __builtin_amdgcn_fmed3f(best[mtl][j], s, second[mtl][j]);
                    best[mtl][j]   = fminf(best[mtl][j], s);
                    bidx[mtl][j]   = lt ? code : bidx[mtl][j];
                }
            }
        }
    }

    #pragma unroll
    for (int m = 0; m < 2; ++m)
        #pragma unroll
        for (int j = 0; j < 4; ++j) {
            float bv = best[m][j], sv = second[m][j]; int bi = bidx[m][j];
            #pragma unroll
            for (int d = 1; d < 16; d <<= 1) {
                float ob = __shfl_xor(bv, d, 64);
                float os = __shfl_xor(sv, d, 64);
                int   oi = __shfl_xor(bi, d, 64);
                float loser = fmaxf(bv, ob);
                sv = fminf(fminf(sv, os), loser);
                bool sw = ob < bv;
                bv = fminf(bv, ob);
                bi = sw ? oi : bi;
            }
            if ((lane & 15) == 0) {
                int t = t0 + (wv*2 + m)*16 + (lane >> 4)*4 + j;
                if (t < T) {
                    out[((size_t)cb*64 + b)*T + t] = bi;
                    if (sv - bv < VQ_MARGIN) {
                        int pos = atomicAdd(&cnt[cb], 1);
                        list[pos] = (b << 11) | t;
                    }
                }
            }
        }
}

// ---------------- VQ rescore: paired same-cb flags, t-major H3 --------------
__global__ __launch_bounds__(256) void vq_rescore_kernel(
    const float* __restrict__ H3, const float* __restrict__ wq,
    const float* __restrict__ bq, const float* __restrict__ cbs,
    const float* __restrict__ ccg, const int* __restrict__ cnt,
    const int* __restrict__ list0, const int* __restrict__ list1,
    int* __restrict__ out)
{
    const int T = 2000;
    __shared__ float hp[4][2][448];
    __shared__ float zsh[4][2][64];
    int tid = threadIdx.x, lane = tid & 63, wv = tid >> 6;
    int cb = blockIdx.y;
    const int* list = cb ? list1 : list0;
    int count = cnt[cb];
    int gw = blockIdx.x * 4 + wv, nw = gridDim.x * 4;

    const float* cbase = cbs + (size_t)cb * 1024 * 64;
    const float* ccb   = ccg + cb * 1024;
    int d = cb * 64 + lane;
    const float4* wp = (const float4*)(wq + (size_t)d * 448);
    float bqd = bq[d];

    for (int i0 = gw * 2; i0 < count; i0 += nw * 2) {
        int e0 = list[i0];
        int e1 = (i0 + 1 < count) ? list[i0 + 1] : e0;
        int b0 = e0 >> 11, t0 = e0 & 2047;
        int b1 = e1 >> 11, t1 = e1 & 2047;

        size_t base0 = (size_t)b0 * T * 64;
        size_t base1 = (size_t)b1 * T * 64;
        #pragma unroll
        for (int kk = 0; kk < 7; ++kk) {
            int a0 = t0 - 6 + kk, a1 = t1 - 6 + kk;
            hp[wv][0][lane * 7 + kk] = (a0 >= 0) ? H3[base0 + (size_t)a0 * 64 + lane] : 0.0f;
            hp[wv][1][lane * 7 + kk] = (a1 >= 0) ? H3[base1 + (size_t)a1 * 64 + lane] : 0.0f;
        }

        float p00=0.f,p01=0.f,p02=0.f,p03=0.f, p10=0.f,p11=0.f,p12=0.f,p13=0.f;
        #pragma unroll 8
        for (int q = 0; q < 112; ++q) {
            float4 w4 = wp[q];
            float4 h0 = *(const float4*)&hp[wv][0][4 * q];
            float4 h1 = *(const float4*)&hp[wv][1][4 * q];
            p00 = fmaf(w4.x, h0.x, p00); p01 = fmaf(w4.y, h0.y, p01);
            p02 = fmaf(w4.z, h0.z, p02); p03 = fmaf(w4.w, h0.w, p03);
            p10 = fmaf(w4.x, h1.x, p10); p11 = fmaf(w4.y, h1.y, p11);
            p12 = fmaf(w4.z, h1.z, p12); p13 = fmaf(w4.w, h1.w, p13);
        }
        float z0 = (p00 + p01) + (p02 + p03) + bqd; z0 = z0 > 0.f ? z0 : expm1f(z0);
        float z1 = (p10 + p11) + (p12 + p13) + bqd; z1 = z1 > 0.f ? z1 : expm1f(z1);
        zsh[wv][0][lane] = z0;
        zsh[wv][1][lane] = z1;

        float bv0 = 3.4e38f, bv1 = 3.4e38f; int bi0 = 0, bi1 = 0;
        for (int ii = 0; ii < 16; ++ii) {
            int code = ii * 64 + lane;
            const float4* cp = (const float4*)(cbase + (size_t)code * 64);
            float d00=0.f,d01=0.f,d02=0.f,d03=0.f, d10=0.f,d11=0.f,d12=0.f,d13=0.f;
            #pragma unroll
            for (int q = 0; q < 16; ++q) {
                float4 cv = cp[q];
                float4 za = *(const float4*)&zsh[wv][0][4 * q];
                float4 zc = *(const float4*)&zsh[wv][1][4 * q];
                d00 = fmaf(za.x, cv.x, d00); d01 = fmaf(za.y, cv.y, d01);
                d02 = fmaf(za.z, cv.z, d02); d03 = fmaf(za.w, cv.w, d03);
                d10 = fmaf(zc.x, cv.x, d10); d11 = fmaf(zc.y, cv.y, d11);
                d12 = fmaf(zc.z, cv.z, d12); d13 = fmaf(zc.w, cv.w, d13);
            }
            float cc0 = ccb[code];
            float s0 = fmaf(-2.0f, (d00 + d01) + (d02 + d03), cc0);
            float s1 = fmaf(-2.0f, (d10 + d11) + (d12 + d13), cc0);
            if (s0 < bv0) { bv0 = s0; bi0 = code; }
            if (s1 < bv1) { bv1 = s1; bi1 = code; }
        }
        #pragma unroll
        for (int dd = 1; dd < 64; dd <<= 1) {
            float ov0 = __shfl_xor(bv0, dd, 64); int oi0 = __shfl_xor(bi0, dd, 64);
            if (ov0 < bv0 || (ov0 == bv0 && oi0 < bi0)) { bv0 = ov0; bi0 = oi0; }
            float ov1 = __shfl_xor(bv1, dd, 64); int oi1 = __shfl_xor(bi1, dd, 64);
            if (ov1 < bv1 || (ov1 == bv1 && oi1 < bi1)) { bv1 = ov1; bi1 = oi1; }
        }
        if (lane == 0) {
            out[((size_t)cb * 64 + b0) * T + t0] = bi0;
            out[((size_t)cb * 64 + b1) * T + t1] = bi1;
        }
    }
}

extern "C" void kernel_launch(void* const* d_in, const int* in_sizes, int n_in,
                              void* d_out, int out_size, void* d_ws, size_t ws_size,
                              hipStream_t stream)
{
    const float* x   = (const float*)d_in[0];
    const float* w0  = (const float*)d_in[1];
    const float* b0  = (const float*)d_in[2];
    const float* w1  = (const float*)d_in[3];
    const float* b1  = (const float*)d_in[4];
    const float* w2  = (const float*)d_in[5];
    const float* b2  = (const float*)d_in[6];
    const float* w3  = (const float*)d_in[7];
    const float* b3  = (const float*)d_in[8];
    const float* wq  = (const float*)d_in[9];
    const float* bq  = (const float*)d_in[10];
    const float* cbs = (const float*)d_in[11];
    int* out = (int*)d_out;

    // two 98,304,000-byte regions (proven footprint)
    char* r1 = (char*)d_ws;
    char* r2 = r1 + 98304000;
    float* H0 = (float*)r1;               // [64][12000][32] fp32 t-major (phase-split)
    float* H1 = (float*)r2;               // [64][6000][64]  (phase-split)
    float* H2 = (float*)r1;               // [64][6000][64]  (over dead H0)
    float* H3 = (float*)r2;               // [64][2000][64]  (over dead H1)
    float* z  = (float*)(r2 + 32768000);  // [64][128][2000] fp32

    // weight fragments in d_out (dead until vq_mfma rewrites it)
    short* wf1 = (short*)d_out;           // 12288 shorts
    short* wf2 = wf1 + 12288;             // 49152
    short* wf3 = wf1 + 61440;             // 86016
    short* wf4 = wf1 + 147456;            // 172032 -> ends at 319488 shorts

    // VQ prep data in r1 (free after conv3 consumes H2)
    short* cbf   = (short*)r1;
    float* cc    = (float*)(r1 + 524288);
    int*   cnt   = (int*)(r1 + 540000);
    int*   list0 = (int*)(r1 + 1000000);
    int*   list1 = (int*)(r1 + 2100000);

    // weight prep (reads inputs only)
    wprep3_ps_kernel<16, 32><<<1, 32, 0, stream>>>(w1, wf1);
    wprep3_ps_kernel<32, 64><<<1, 64, 0, stream>>>(w2, wf2);
    wprep3_kernel<64, 64, 7><<<1, 64, 0, stream>>>(w3, wf3);
    wprep3_kernel<64, 128, 7><<<1, 128, 0, stream>>>(wq, wf4);

    // conv0: x -> H0 (fp32 t-major, phase-split)
    conv0_kernel<<<dim3(188, 64), 256, 0, stream>>>(x, w0, b0, H0);
    // conv1: H0 -> H1, stride-1 K=4 over 32ch, phase-split out
    conv_mfma3_kernel<1, 32, 32, 2, 4, 3, 1><<<dim3(94, 64), 256, 0, stream>>>(
        H0, wf1, b1, H1, 12000, 12000);
    // conv2: H1 -> H2, stride-1 K=4 over 64ch, t-major out
    conv_mfma3_kernel<1, 64, 64, 2, 4, 3, 0><<<dim3(47, 64), 256, 0, stream>>>(
        H1, wf2, b2, H2, 6000, 6000);
    // conv3: H2 -> H3, stride 3, K=7, t-major out
    conv_mfma3_kernel<3, 64, 64, 1, 7, 6, 0><<<dim3(32, 64), 256, 0, stream>>>(
        H2, wf3, b3, H3, 6000, 2000);

    // VQ prep into r1 (H2 now dead)
    vq_prep_kernel<<<8, 256, 0, stream>>>(cbs, cc, cbf);
    zero_cnt_kernel<<<1, 64, 0, stream>>>(cnt);

    // conv4: H3 -> z (fp32 [co][t]), stride 1, K=7
    conv_mfma3_kernel<1, 64, 128, 2, 7, 6, 2><<<dim3(16, 64), 256, 0, stream>>>(
        H3, wf4, bq, z, 2000, 2000);

    // VQ: MFMA scores + per-cb flag lists, then paired exact rescore
    vq_mfma_kernel<<<dim3(16, 2, 64), 256, 0, stream>>>(z, cbf, cc, out, cnt, list0, list1);
    vq_rescore_kernel<<<dim3(512, 2), 256, 0, stream>>>(H3, wq, bq, cbs, cc, cnt, list0, list1, out);
}

// Round 18
// 675.680 us; speedup vs baseline: 1.1318x; 1.1318x over previous
//
#include <hip/hip_runtime.h>
#include <hip/hip_bf16.h>
#include <cstddef>

// ---------------------------------------------------------------------------
// EncoderModule: 5x causal conv1d (K=7) + ELU, then 2x VQ argmin (1024 codes, D=64)
// B=64, L=48000, strides 2,2,2,3,1; channels 1->16->32->64->64->128
// Output: int32 indices, shape (2, 64, 2000)
//
// Inter-layer tensors: fp32, t-major [t][ci]. Convs 1-4: 6-term split3-bf16
// MFMA (round-14 numerics, passed absmax 0).
// VQ: codebook pre-scaled by -2, ||c||^2 folded into MFMA accumulator init,
// med3 best/second; LDS z-frag/B-chunk buffers UNIONED (32KB -> 4 blocks/CU),
// DIRECT per-chunk LDS copy (r16/r17 register prefetch spilled to scratch:
// 460MB WRITE_SIZE); waves_per_eu pinned (4,4) so the allocator keeps the
// 128-VGPR budget. gap < 0.04 -> flag; paired exact rescore.
// ---------------------------------------------------------------------------

using bf16x8 = __attribute__((ext_vector_type(8))) short;
using s16x4  = __attribute__((ext_vector_type(4))) short;
using f32x4  = __attribute__((ext_vector_type(4))) float;

static __device__ __forceinline__ short f2bf(float f) {
    __hip_bfloat16 h = __float2bfloat16(f);   // RNE
    union { __hip_bfloat16 h; short s; } u; u.h = h;
    return u.s;
}
static __device__ __forceinline__ float bf2f(short s) {
    union { unsigned u; float f; } v;
    v.u = ((unsigned)(unsigned short)s) << 16;
    return v.f;
}
static __device__ __forceinline__ void split3(float v, short& s0, short& s1, short& s2) {
    s0 = f2bf(v);  float r1 = v  - bf2f(s0);   // exact
    s1 = f2bf(r1); float r2 = r1 - bf2f(s1);   // exact
    s2 = f2bf(r2);                             // residual ~2^-24 |v|
}
static __device__ __forceinline__ float elu(float v) {
    return v > 0.0f ? v : expm1f(v);
}

// ---------------- conv0: fp32 VALU, t-major phase-split store ---------------
__global__ __launch_bounds__(256) void conv0_kernel(
    const float* __restrict__ x, const float* __restrict__ w,
    const float* __restrict__ bias, float* __restrict__ H0)
{
    __shared__ float xs[261];                  // (128-1)*2+7
    int tb = blockIdx.x, b = blockIdx.y;
    int t0 = tb * 128;
    int tid = threadIdx.x, lane = tid & 63;
    int wv = __builtin_amdgcn_readfirstlane(tid >> 6);

    const float* xb = x + (size_t)b * 48000;
    int g0 = t0 * 2 - 6;
    for (int i = tid; i < 261; i += 256) {
        int gx = g0 + i;
        xs[i] = (gx >= 0 && gx < 48000) ? xb[gx] : 0.0f;
    }
    __syncthreads();

    int co0 = wv * 4;
    float acc[4][2];
    #pragma unroll
    for (int c = 0; c < 4; ++c) { acc[c][0] = 0.f; acc[c][1] = 0.f; }

    float xw[2][7];
    #pragma unroll
    for (int u = 0; u < 2; ++u)
        #pragma unroll
        for (int k = 0; k < 7; ++k)
            xw[u][k] = xs[(lane + 64 * u) * 2 + k];
    #pragma unroll
    for (int c = 0; c < 4; ++c) {
        const float* wp = w + (size_t)(co0 + c) * 7;   // s_load
        #pragma unroll
        for (int k = 0; k < 7; ++k) {
            float wk = wp[k];
            acc[c][0] = fmaf(wk, xw[0][k], acc[c][0]);
            acc[c][1] = fmaf(wk, xw[1][k], acc[c][1]);
        }
    }

    #pragma unroll
    for (int u = 0; u < 2; ++u) {
        int t = t0 + lane + 64 * u;
        if (t < 24000) {
            float4 vv;
            vv.x = elu(acc[0][u] + bias[co0 + 0]);
            vv.y = elu(acc[1][u] + bias[co0 + 1]);
            vv.z = elu(acc[2][u] + bias[co0 + 2]);
            vv.w = elu(acc[3][u] + bias[co0 + 3]);
            *(float4*)(H0 + ((size_t)b * 12000 + (t >> 1)) * 32 + (t & 1) * 16 + co0) = vv;
        }
    }
}

// ---------------- weight prep: 3-level bf16 A-fragments ---------------------
template<int CIN, int COUT, int TAPS>
__global__ void wprep3_kernel(const float* __restrict__ w, short* __restrict__ frag)
{
    constexpr int KC = CIN / 32;
    int co = threadIdx.x;
    if (co >= COUT) return;
    int mt = co >> 4, nc = co & 15;
    for (int kc = 0; kc < KC; ++kc)
        for (int k = 0; k < TAPS; ++k)
            #pragma unroll
            for (int lh = 0; lh < 4; ++lh) {
                bf16x8 p0, p1, p2;
                #pragma unroll
                for (int j = 0; j < 8; ++j) {
                    int ci = kc * 32 + lh * 8 + j;
                    float f = w[(size_t)co * CIN * 7 + ci * 7 + k];
                    short a, bb, c; split3(f, a, bb, c);
                    p0[j] = a; p1[j] = bb; p2[j] = c;
                }
                size_t base = ((size_t)(mt * KC + kc) * TAPS + k) * 3;
                int off = (lh * 16 + nc) * 8;
                *(bf16x8*)(frag + (base + 0) * 512 + off) = p0;
                *(bf16x8*)(frag + (base + 1) * 512 + off) = p1;
                *(bf16x8*)(frag + (base + 2) * 512 + off) = p2;
            }
}

// phase-split packing (stride-2 K=7 -> stride-1 K=4 over doubled channels)
template<int CINH, int COUT>
__global__ void wprep3_ps_kernel(const float* __restrict__ w, short* __restrict__ frag)
{
    constexpr int CIN = 2 * CINH;
    constexpr int KC  = CIN / 32;
    int co = threadIdx.x;
    if (co >= COUT) return;
    int mt = co >> 4, nc = co & 15;
    for (int kc = 0; kc < KC; ++kc)
        for (int m = 0; m < 4; ++m)
            #pragma unroll
            for (int lh = 0; lh < 4; ++lh) {
                bf16x8 p0, p1, p2;
                #pragma unroll
                for (int j = 0; j < 8; ++j) {
                    int cp = kc * 32 + lh * 8 + j;
                    float f;
                    if (cp < CINH)  f = w[(size_t)co * CINH * 7 + cp * 7 + 2 * m];
                    else if (m < 3) f = w[(size_t)co * CINH * 7 + (cp - CINH) * 7 + 2 * m + 1];
                    else            f = 0.0f;
                    short a, bb, c; split3(f, a, bb, c);
                    p0[j] = a; p1[j] = bb; p2[j] = c;
                }
                size_t base = ((size_t)(mt * KC + kc) * 4 + m) * 3;
                int off = (lh * 16 + nc) * 8;
                *(bf16x8*)(frag + (base + 0) * 512 + off) = p0;
                *(bf16x8*)(frag + (base + 1) * 512 + off) = p1;
                *(bf16x8*)(frag + (base + 2) * 512 + off) = p2;
            }
}

// ---------------- conv via 6-term split3-bf16 MFMA, t-major fp32 I/O --------
template<int S, int CIN, int COUT, int NTL, int TAPS, int PAD, int OUTMODE>
__global__ __launch_bounds__(256) void conv_mfma3_kernel(
    const float* __restrict__ Hin, const short* __restrict__ wfrag,
    const float* __restrict__ bias, float* __restrict__ Hout,
    int Lin, int Lout)
{
    constexpr int KC   = CIN / 32;
    constexpr int MT   = COUT / 16;
    constexpr int NT   = NTL * 64;
    constexpr int ROWS = (NT - 1) * S + TAPS;
    constexpr int ROWB = CIN * 2;
    constexpr int NSL  = CIN / 4;
    __shared__ __align__(16) short pl0[ROWS * CIN];
    __shared__ __align__(16) short pl1[ROWS * CIN];
    __shared__ __align__(16) short pl2[ROWS * CIN];

    int nb = blockIdx.x, b = blockIdx.y;
    int t0 = nb * NT;
    int tid = threadIdx.x, lane = tid & 63, wv = tid >> 6;
    int g0 = t0 * S - PAD;

    const float* inb = Hin + (size_t)b * Lin * CIN;
    for (int e = tid; e < ROWS * NSL; e += 256) {
        int rr = e / NSL, sl = e % NSL;
        int g = g0 + rr;
        float4 v = {0.f, 0.f, 0.f, 0.f};
        if (g >= 0 && g < Lin)
            v = *(const float4*)(inb + (size_t)g * CIN + sl * 4);
        int xr = (CIN == 64) ? (rr & 7) : ((rr >> 1) & 3);
        int byte = rr * ROWB + ((((sl >> 1) ^ xr) << 4) | ((sl & 1) << 3));
        s16x4 q0, q1, q2;
        short a0, a1, a2;
        split3(v.x, a0, a1, a2); q0[0] = a0; q1[0] = a1; q2[0] = a2;
        split3(v.y, a0, a1, a2); q0[1] = a0; q1[1] = a1; q2[1] = a2;
        split3(v.z, a0, a1, a2); q0[2] = a0; q1[2] = a1; q2[2] = a2;
        split3(v.w, a0, a1, a2); q0[3] = a0; q1[3] = a1; q2[3] = a2;
        *(s16x4*)((char*)pl0 + byte) = q0;
        *(s16x4*)((char*)pl1 + byte) = q1;
        *(s16x4*)((char*)pl2 + byte) = q2;
    }
    __syncthreads();

    f32x4 acc[NTL][MT];
    #pragma unroll
    for (int n = 0; n < NTL; ++n)
        #pragma unroll
        for (int m = 0; m < MT; ++m) acc[n][m] = (f32x4){0.f, 0.f, 0.f, 0.f};

    int ncol = lane & 15, nq = lane >> 4;

    for (int k = 0; k < TAPS; ++k) {
        #pragma unroll
        for (int kc = 0; kc < KC; ++kc) {
            int colb = (kc * 32 + nq * 8) * 2;
            bf16x8 B0[NTL], B1[NTL], B2[NTL];
            #pragma unroll
            for (int ntl = 0; ntl < NTL; ++ntl) {
                int r  = S * ((wv * NTL + ntl) * 16 + ncol) + k;
                int xr = (CIN == 64) ? (r & 7) : ((r >> 1) & 3);
                int byte = r * ROWB + (colb ^ (xr << 4));
                B0[ntl] = *(const bf16x8*)((char*)pl0 + byte);
                B1[ntl] = *(const bf16x8*)((char*)pl1 + byte);
                B2[ntl] = *(const bf16x8*)((char*)pl2 + byte);
            }
            #pragma unroll
            for (int m = 0; m < MT; ++m) {
                size_t base = ((size_t)(m * KC + kc) * TAPS + k) * 3;
                bf16x8 a0 = *(const bf16x8*)(wfrag + (base + 0) * 512 + lane * 8);
                bf16x8 a1 = *(const bf16x8*)(wfrag + (base + 1) * 512 + lane * 8);
                bf16x8 a2 = *(const bf16x8*)(wfrag + (base + 2) * 512 + lane * 8);
                #pragma unroll
                for (int ntl = 0; ntl < NTL; ++ntl) {
                    f32x4 a = acc[ntl][m];
                    a = __builtin_amdgcn_mfma_f32_16x16x32_bf16(a0, B0[ntl], a, 0, 0, 0);
                    a = __builtin_amdgcn_mfma_f32_16x16x32_bf16(a1, B0[ntl], a, 0, 0, 0);
                    a = __builtin_amdgcn_mfma_f32_16x16x32_bf16(a2, B0[ntl], a, 0, 0, 0);
                    a = __builtin_amdgcn_mfma_f32_16x16x32_bf16(a0, B1[ntl], a, 0, 0, 0);
                    a = __builtin_amdgcn_mfma_f32_16x16x32_bf16(a1, B1[ntl], a, 0, 0, 0);
                    a = __builtin_amdgcn_mfma_f32_16x16x32_bf16(a0, B2[ntl], a, 0, 0, 0);
                    acc[ntl][m] = a;
                }
            }
        }
    }

    #pragma unroll
    for (int ntl = 0; ntl < NTL; ++ntl) {
        int n = t0 + (wv * NTL + ntl) * 16 + ncol;
        if (n < Lout) {
            #pragma unroll
            for (int m = 0; m < MT; ++m) {
                int co0 = m * 16 + nq * 4;
                float4 bb = *(const float4*)(bias + co0);
                float4 vv;
                vv.x = elu(acc[ntl][m][0] + bb.x);
                vv.y = elu(acc[ntl][m][1] + bb.y);
                vv.z = elu(acc[ntl][m][2] + bb.z);
                vv.w = elu(acc[ntl][m][3] + bb.w);
                if constexpr (OUTMODE == 0) {
                    *(float4*)(Hout + ((size_t)b * Lout + n) * COUT + co0) = vv;
                } else if constexpr (OUTMODE == 1) {
                    *(float4*)(Hout + ((size_t)b * (Lout >> 1) + (n >> 1)) * (2 * COUT)
                               + (n & 1) * COUT + co0) = vv;
                } else {
                    Hout[((size_t)b * COUT + co0 + 0) * Lout + n] = vv.x;
                    Hout[((size_t)b * COUT + co0 + 1) * Lout + n] = vv.y;
                    Hout[((size_t)b * COUT + co0 + 2) * Lout + n] = vv.z;
                    Hout[((size_t)b * COUT + co0 + 3) * Lout + n] = vv.w;
                }
            }
        }
    }
}

// ---------------- VQ prep: cc (fp32, +||c||^2) + (-2c) hi/lo bf16 B-frags ---
__global__ __launch_bounds__(256) void vq_prep_kernel(
    const float* __restrict__ cbs, float* __restrict__ cc, short* __restrict__ cbf)
{
    int c = blockIdx.x * 256 + threadIdx.x;   // 0..2047
    if (c >= 2048) return;
    int cb = c >> 10, nl = c & 1023;
    const float* row = cbs + (size_t)c * 64;
    float v[64];
    float s = 0.f;
    #pragma unroll
    for (int i = 0; i < 16; ++i) {
        float4 q = ((const float4*)row)[i];
        v[4*i+0] = q.x; v[4*i+1] = q.y; v[4*i+2] = q.z; v[4*i+3] = q.w;
        s += q.x*q.x + q.y*q.y + q.z*q.z + q.w*q.w;
    }
    cc[c] = s;
    int nt = nl >> 4, nc = nl & 15;
    #pragma unroll
    for (int kc = 0; kc < 2; ++kc)
        #pragma unroll
        for (int lh = 0; lh < 4; ++lh) {
            bf16x8 ph, pl;
            #pragma unroll
            for (int j = 0; j < 8; ++j) {
                float f = -2.0f * v[kc*32 + lh*8 + j];   // exact scaling
                short h = f2bf(f);
                ph[j] = h;
                pl[j] = f2bf(f - bf2f(h));
            }
            size_t base = ((((size_t)cb*64 + nt)*2 + kc)*2);
            *(bf16x8*)(cbf + ((base + 0)*64 + (lh*16 + nc)) * 8) = ph;
            *(bf16x8*)(cbf + ((base + 1)*64 + (lh*16 + nc)) * 8) = pl;
        }
}

__global__ void zero_cnt_kernel(int* cnt) {
    if (threadIdx.x == 0 && blockIdx.x == 0) { cnt[0] = 0; cnt[1] = 0; }
}

// ---------------- VQ main: MFMA scores, unioned LDS, direct chunk copy ------
#define VQ_MARGIN 0.04f

__global__ __launch_bounds__(256)
__attribute__((amdgpu_waves_per_eu(4, 4)))
void vq_mfma_kernel(
    const float* __restrict__ z, const short* __restrict__ cbf,
    const float* __restrict__ ccg, int* __restrict__ out,
    int* __restrict__ cnt, int* __restrict__ list0, int* __restrict__ list1)
{
    // 32 KB union: z A-fragments (staging phase) then B-frag chunk (main loop)
    __shared__ __align__(16) short sbuf[16384];
    short* zf0 = sbuf;            // [8 mt][2 kc][64 lane][8] hi
    short* zf1 = sbuf + 8192;     // lo
    short* cbc = sbuf;            // chunk: [8 ntl][2 kc][2 hl][64 lane][8]

    const int T = 2000;
    int mblk = blockIdx.x;
    int cb   = blockIdx.y;
    int b    = blockIdx.z;
    int t0   = mblk * 128;
    int tid  = threadIdx.x;
    int lane = tid & 63;
    int wv   = tid >> 6;
    int* list = cb ? list1 : list0;

    // ---- stage z -> hi/lo A-fragments (b128 rows, conflict-free) ----
    const float* zb = z + ((size_t)b*128 + (size_t)cb*64) * T;
    for (int e = tid; e < 128 * 8; e += 256) {
        int tl = e & 127;
        int d0 = (e >> 7) * 8;
        int tt = t0 + tl; if (tt > T - 1) tt = T - 1;
        bf16x8 hi, lo;
        #pragma unroll
        for (int jj = 0; jj < 8; ++jj) {
            float v = zb[(size_t)(d0 + jj) * T + tt];
            short h = f2bf(v);
            hi[jj] = h;
            lo[jj] = f2bf(v - bf2f(h));
        }
        int mt = tl >> 4, kc = d0 >> 5;
        int lw = ((d0 & 31) >> 3) * 16 + (tl & 15);
        int idx = ((mt*2 + kc)*64 + lw) * 8;
        *(bf16x8*)&zf0[idx] = hi;
        *(bf16x8*)&zf1[idx] = lo;
    }
    __syncthreads();

    bf16x8 ah[2][2], al[2][2];
    #pragma unroll
    for (int mtl = 0; mtl < 2; ++mtl)
        #pragma unroll
        for (int kc = 0; kc < 2; ++kc) {
            int idx = ((((wv*2+mtl)*2 + kc)*64) + lane)*8;
            ah[mtl][kc] = *(const bf16x8*)&zf0[idx];
            al[mtl][kc] = *(const bf16x8*)&zf1[idx];
        }

    float best[2][4], second[2][4]; int bidx[2][4];
    #pragma unroll
    for (int m = 0; m < 2; ++m)
        #pragma unroll
        for (int j = 0; j < 4; ++j) { best[m][j] = 3.4e38f; second[m][j] = 3.4e38f; bidx[m][j] = 0; }

    const short* cbase = cbf + (size_t)cb * (64*2*2*64*8);
    const float* ccb   = ccg + cb * 1024;
    int c15 = lane & 15;

    for (int ch = 0; ch < 8; ++ch) {
        __syncthreads();   // all reads of sbuf (zf regs or prev chunk) done
        {
            const float4* src = (const float4*)(cbase + (size_t)ch * (8*2*2*64*8));
            float4* dst = (float4*)cbc;
            #pragma unroll
            for (int i = 0; i < 8; ++i) dst[tid + 256*i] = src[tid + 256*i];
        }
        __syncthreads();

        #pragma unroll
        for (int ntl = 0; ntl < 8; ++ntl) {
            bf16x8 b0h = *(const bf16x8*)&cbc[(((ntl*2 + 0)*2 + 0)*64 + lane)*8];
            bf16x8 b0l = *(const bf16x8*)&cbc[(((ntl*2 + 0)*2 + 1)*64 + lane)*8];
            bf16x8 b1h = *(const bf16x8*)&cbc[(((ntl*2 + 1)*2 + 0)*64 + lane)*8];
            bf16x8 b1l = *(const bf16x8*)&cbc[(((ntl*2 + 1)*2 + 1)*64 + lane)*8];
            int  code = ch*128 + ntl*16 + c15;
            float ccv = ccb[code];                 // L1-resident 8KB table
            #pragma unroll
            for (int mtl = 0; mtl < 2; ++mtl) {
                f32x4 p = {ccv, ccv, ccv, ccv};
                __builtin_amdgcn_s_setprio(1);
                p = __builtin_amdgcn_mfma_f32_16x16x32_bf16(ah[mtl][0], b0h, p, 0, 0, 0);
                p = __builtin_amdgcn_mfma_f32_16x16x32_bf16(al[mtl][0], b0h, p, 0, 0, 0);
                p = __builtin_amdgcn_mfma_f32_16x16x32_bf16(ah[mtl][0], b0l, p, 0, 0, 0);
                p = __builtin_amdgcn_mfma_f32_16x16x32_bf16(ah[mtl][1], b1h, p, 0, 0, 0);
                p = __builtin_amdgcn_mfma_f32_16x16x32_bf16(al[mtl][1], b1h, p, 0, 0, 0);
                p = __builtin_amdgcn_mfma_f32_16x16x32_bf16(ah[mtl][1], b1l, p, 0, 0, 0);
                __builtin_amdgcn_s_setprio(0);
                #pragma unroll
                for (int j = 0; j < 4; ++j) {
                    float s = p[j];
                    bool lt = s < best[mtl][j];
                    second[mtl][j] = __builtin_amdgcn_fmed3f(best[mtl][j], s, second[mtl][j]);
                    best[mtl][j]   = fminf(best[mtl][j], s);
                    bidx[mtl][j]   = lt ? code : bidx[mtl][j];
                }
            }
        }
    }

    #pragma unroll
    for (int m = 0; m < 2; ++m)
        #pragma unroll
        for (int j = 0; j < 4; ++j) {
            float bv = best[m][j], sv = second[m][j]; int bi = bidx[m][j];
            #pragma unroll
            for (int d = 1; d < 16; d <<= 1) {
                float ob = __shfl_xor(bv, d, 64);
                float os = __shfl_xor(sv, d, 64);
                int   oi = __shfl_xor(bi, d, 64);
                float loser = fmaxf(bv, ob);
                sv = fminf(fminf(sv, os), loser);
                bool sw = ob < bv;
                bv = fminf(bv, ob);
                bi = sw ? oi : bi;
            }
            if ((lane & 15) == 0) {
                int t = t0 + (wv*2 + m)*16 + (lane >> 4)*4 + j;
                if (t < T) {
                    out[((size_t)cb*64 + b)*T + t] = bi;
                    if (sv - bv < VQ_MARGIN) {
                        int pos = atomicAdd(&cnt[cb], 1);
                        list[pos] = (b << 11) | t;
                    }
                }
            }
        }
}

// ---------------- VQ rescore: paired same-cb flags, t-major H3 --------------
__global__ __launch_bounds__(256) void vq_rescore_kernel(
    const float* __restrict__ H3, const float* __restrict__ wq,
    const float* __restrict__ bq, const float* __restrict__ cbs,
    const float* __restrict__ ccg, const int* __restrict__ cnt,
    const int* __restrict__ list0, const int* __restrict__ list1,
    int* __restrict__ out)
{
    const int T = 2000;
    __shared__ float hp[4][2][448];
    __shared__ float zsh[4][2][64];
    int tid = threadIdx.x, lane = tid & 63, wv = tid >> 6;
    int cb = blockIdx.y;
    const int* list = cb ? list1 : list0;
    int count = cnt[cb];
    int gw = blockIdx.x * 4 + wv, nw = gridDim.x * 4;

    const float* cbase = cbs + (size_t)cb * 1024 * 64;
    const float* ccb   = ccg + cb * 1024;
    int d = cb * 64 + lane;
    const float4* wp = (const float4*)(wq + (size_t)d * 448);
    float bqd = bq[d];

    for (int i0 = gw * 2; i0 < count; i0 += nw * 2) {
        int e0 = list[i0];
        int e1 = (i0 + 1 < count) ? list[i0 + 1] : e0;
        int b0 = e0 >> 11, t0 = e0 & 2047;
        int b1 = e1 >> 11, t1 = e1 & 2047;

        size_t base0 = (size_t)b0 * T * 64;
        size_t base1 = (size_t)b1 * T * 64;
        #pragma unroll
        for (int kk = 0; kk < 7; ++kk) {
            int a0 = t0 - 6 + kk, a1 = t1 - 6 + kk;
            hp[wv][0][lane * 7 + kk] = (a0 >= 0) ? H3[base0 + (size_t)a0 * 64 + lane] : 0.0f;
            hp[wv][1][lane * 7 + kk] = (a1 >= 0) ? H3[base1 + (size_t)a1 * 64 + lane] : 0.0f;
        }

        float p00=0.f,p01=0.f,p02=0.f,p03=0.f, p10=0.f,p11=0.f,p12=0.f,p13=0.f;
        #pragma unroll 8
        for (int q = 0; q < 112; ++q) {
            float4 w4 = wp[q];
            float4 h0 = *(const float4*)&hp[wv][0][4 * q];
            float4 h1 = *(const float4*)&hp[wv][1][4 * q];
            p00 = fmaf(w4.x, h0.x, p00); p01 = fmaf(w4.y, h0.y, p01);
            p02 = fmaf(w4.z, h0.z, p02); p03 = fmaf(w4.w, h0.w, p03);
            p10 = fmaf(w4.x, h1.x, p10); p11 = fmaf(w4.y, h1.y, p11);
            p12 = fmaf(w4.z, h1.z, p12); p13 = fmaf(w4.w, h1.w, p13);
        }
        float z0 = (p00 + p01) + (p02 + p03) + bqd; z0 = z0 > 0.f ? z0 : expm1f(z0);
        float z1 = (p10 + p11) + (p12 + p13) + bqd; z1 = z1 > 0.f ? z1 : expm1f(z1);
        zsh[wv][0][lane] = z0;
        zsh[wv][1][lane] = z1;

        float bv0 = 3.4e38f, bv1 = 3.4e38f; int bi0 = 0, bi1 = 0;
        for (int ii = 0; ii < 16; ++ii) {
            int code = ii * 64 + lane;
            const float4* cp = (const float4*)(cbase + (size_t)code * 64);
            float d00=0.f,d01=0.f,d02=0.f,d03=0.f, d10=0.f,d11=0.f,d12=0.f,d13=0.f;
            #pragma unroll
            for (int q = 0; q < 16; ++q) {
                float4 cv = cp[q];
                float4 za = *(const float4*)&zsh[wv][0][4 * q];
                float4 zc = *(const float4*)&zsh[wv][1][4 * q];
                d00 = fmaf(za.x, cv.x, d00); d01 = fmaf(za.y, cv.y, d01);
                d02 = fmaf(za.z, cv.z, d02); d03 = fmaf(za.w, cv.w, d03);
                d10 = fmaf(zc.x, cv.x, d10); d11 = fmaf(zc.y, cv.y, d11);
                d12 = fmaf(zc.z, cv.z, d12); d13 = fmaf(zc.w, cv.w, d13);
            }
            float cc0 = ccb[code];
            float s0 = fmaf(-2.0f, (d00 + d01) + (d02 + d03), cc0);
            float s1 = fmaf(-2.0f, (d10 + d11) + (d12 + d13), cc0);
            if (s0 < bv0) { bv0 = s0; bi0 = code; }
            if (s1 < bv1) { bv1 = s1; bi1 = code; }
        }
        #pragma unroll
        for (int dd = 1; dd < 64; dd <<= 1) {
            float ov0 = __shfl_xor(bv0, dd, 64); int oi0 = __shfl_xor(bi0, dd, 64);
            if (ov0 < bv0 || (ov0 == bv0 && oi0 < bi0)) { bv0 = ov0; bi0 = oi0; }
            float ov1 = __shfl_xor(bv1, dd, 64); int oi1 = __shfl_xor(bi1, dd, 64);
            if (ov1 < bv1 || (ov1 == bv1 && oi1 < bi1)) { bv1 = ov1; bi1 = oi1; }
        }
        if (lane == 0) {
            out[((size_t)cb * 64 + b0) * T + t0] = bi0;
            out[((size_t)cb * 64 + b1) * T + t1] = bi1;
        }
    }
}

extern "C" void kernel_launch(void* const* d_in, const int* in_sizes, int n_in,
                              void* d_out, int out_size, void* d_ws, size_t ws_size,
                              hipStream_t stream)
{
    const float* x   = (const float*)d_in[0];
    const float* w0  = (const float*)d_in[1];
    const float* b0  = (const float*)d_in[2];
    const float* w1  = (const float*)d_in[3];
    const float* b1  = (const float*)d_in[4];
    const float* w2  = (const float*)d_in[5];
    const float* b2  = (const float*)d_in[6];
    const float* w3  = (const float*)d_in[7];
    const float* b3  = (const float*)d_in[8];
    const float* wq  = (const float*)d_in[9];
    const float* bq  = (const float*)d_in[10];
    const float* cbs = (const float*)d_in[11];
    int* out = (int*)d_out;

    // two 98,304,000-byte regions (proven footprint)
    char* r1 = (char*)d_ws;
    char* r2 = r1 + 98304000;
    float* H0 = (float*)r1;               // [64][12000][32] fp32 t-major (phase-split)
    float* H1 = (float*)r2;               // [64][6000][64]  (phase-split)
    float* H2 = (float*)r1;               // [64][6000][64]  (over dead H0)
    float* H3 = (float*)r2;               // [64][2000][64]  (over dead H1)
    float* z  = (float*)(r2 + 32768000);  // [64][128][2000] fp32

    // weight fragments in d_out (dead until vq_mfma rewrites it)
    short* wf1 = (short*)d_out;           // 12288 shorts
    short* wf2 = wf1 + 12288;             // 49152
    short* wf3 = wf1 + 61440;             // 86016
    short* wf4 = wf1 + 147456;            // 172032 -> ends at 319488 shorts

    // VQ prep data in r1 (free after conv3 consumes H2)
    short* cbf   = (short*)r1;
    float* cc    = (float*)(r1 + 524288);
    int*   cnt   = (int*)(r1 + 540000);
    int*   list0 = (int*)(r1 + 1000000);
    int*   list1 = (int*)(r1 + 2100000);

    // weight prep (reads inputs only)
    wprep3_ps_kernel<16, 32><<<1, 32, 0, stream>>>(w1, wf1);
    wprep3_ps_kernel<32, 64><<<1, 64, 0, stream>>>(w2, wf2);
    wprep3_kernel<64, 64, 7><<<1, 64, 0, stream>>>(w3, wf3);
    wprep3_kernel<64, 128, 7><<<1, 128, 0, stream>>>(wq, wf4);

    // conv0: x -> H0 (fp32 t-major, phase-split)
    conv0_kernel<<<dim3(188, 64), 256, 0, stream>>>(x, w0, b0, H0);
    // conv1: H0 -> H1, stride-1 K=4 over 32ch, phase-split out
    conv_mfma3_kernel<1, 32, 32, 2, 4, 3, 1><<<dim3(94, 64), 256, 0, stream>>>(
        H0, wf1, b1, H1, 12000, 12000);
    // conv2: H1 -> H2, stride-1 K=4 over 64ch, t-major out
    conv_mfma3_kernel<1, 64, 64, 2, 4, 3, 0><<<dim3(47, 64), 256, 0, stream>>>(
        H1, wf2, b2, H2, 6000, 6000);
    // conv3: H2 -> H3, stride 3, K=7, t-major out
    conv_mfma3_kernel<3, 64, 64, 1, 7, 6, 0><<<dim3(32, 64), 256, 0, stream>>>(
        H2, wf3, b3, H3, 6000, 2000);

    // VQ prep into r1 (H2 now dead)
    vq_prep_kernel<<<8, 256, 0, stream>>>(cbs, cc, cbf);
    zero_cnt_kernel<<<1, 64, 0, stream>>>(cnt);

    // conv4: H3 -> z (fp32 [co][t]), stride 1, K=7
    conv_mfma3_kernel<1, 64, 128, 2, 7, 6, 2><<<dim3(16, 64), 256, 0, stream>>>(
        H3, wf4, bq, z, 2000, 2000);

    // VQ: MFMA scores + per-cb flag lists, then paired exact rescore
    vq_mfma_kernel<<<dim3(16, 2, 64), 256, 0, stream>>>(z, cbf, cc, out, cnt, list0, list1);
    vq_rescore_kernel<<<dim3(512, 2), 256, 0, stream>>>(H3, wq, bq, cbs, cc, cnt, list0, list1, out);
}

// Round 19
// 645.239 us; speedup vs baseline: 1.1852x; 1.0472x over previous
//
#include <hip/hip_runtime.h>
#include <hip/hip_bf16.h>
#include <cstddef>

// ---------------------------------------------------------------------------
// EncoderModule: 5x causal conv1d (K=7) + ELU, then 2x VQ argmin (1024 codes, D=64)
// B=64, L=48000, strides 2,2,2,3,1; channels 1->16->32->64->64->128
// Output: int32 indices, shape (2, 64, 2000)
//
// Inter-layer tensors: fp32, t-major [t][ci]. Convs 1-4: 6-term split3-bf16
// MFMA (round-14 numerics, passed absmax 0).
// VQ: codebook pre-scaled by -2, ||c||^2 folded into MFMA accumulator init,
// med3 best/second; 32KB unioned LDS; direct chunk copy (no reg prefetch —
// r16/r17 spill lesson); waves_per_eu(4,4). gap < 0.04 -> flag.
// Rescore: 4 same-cb flags per wave iteration share the codebook scan and
// w-row stream (L2 traffic/flag 187KB -> ~96KB, 4-way ILP hides latency).
// ---------------------------------------------------------------------------

using bf16x8 = __attribute__((ext_vector_type(8))) short;
using s16x4  = __attribute__((ext_vector_type(4))) short;
using f32x4  = __attribute__((ext_vector_type(4))) float;

static __device__ __forceinline__ short f2bf(float f) {
    __hip_bfloat16 h = __float2bfloat16(f);   // RNE
    union { __hip_bfloat16 h; short s; } u; u.h = h;
    return u.s;
}
static __device__ __forceinline__ float bf2f(short s) {
    union { unsigned u; float f; } v;
    v.u = ((unsigned)(unsigned short)s) << 16;
    return v.f;
}
static __device__ __forceinline__ void split3(float v, short& s0, short& s1, short& s2) {
    s0 = f2bf(v);  float r1 = v  - bf2f(s0);   // exact
    s1 = f2bf(r1); float r2 = r1 - bf2f(s1);   // exact
    s2 = f2bf(r2);                             // residual ~2^-24 |v|
}
static __device__ __forceinline__ float elu(float v) {
    return v > 0.0f ? v : expm1f(v);
}

// ---------------- conv0: fp32 VALU, t-major phase-split store ---------------
__global__ __launch_bounds__(256) void conv0_kernel(
    const float* __restrict__ x, const float* __restrict__ w,
    const float* __restrict__ bias, float* __restrict__ H0)
{
    __shared__ float xs[261];                  // (128-1)*2+7
    int tb = blockIdx.x, b = blockIdx.y;
    int t0 = tb * 128;
    int tid = threadIdx.x, lane = tid & 63;
    int wv = __builtin_amdgcn_readfirstlane(tid >> 6);

    const float* xb = x + (size_t)b * 48000;
    int g0 = t0 * 2 - 6;
    for (int i = tid; i < 261; i += 256) {
        int gx = g0 + i;
        xs[i] = (gx >= 0 && gx < 48000) ? xb[gx] : 0.0f;
    }
    __syncthreads();

    int co0 = wv * 4;
    float acc[4][2];
    #pragma unroll
    for (int c = 0; c < 4; ++c) { acc[c][0] = 0.f; acc[c][1] = 0.f; }

    float xw[2][7];
    #pragma unroll
    for (int u = 0; u < 2; ++u)
        #pragma unroll
        for (int k = 0; k < 7; ++k)
            xw[u][k] = xs[(lane + 64 * u) * 2 + k];
    #pragma unroll
    for (int c = 0; c < 4; ++c) {
        const float* wp = w + (size_t)(co0 + c) * 7;   // s_load
        #pragma unroll
        for (int k = 0; k < 7; ++k) {
            float wk = wp[k];
            acc[c][0] = fmaf(wk, xw[0][k], acc[c][0]);
            acc[c][1] = fmaf(wk, xw[1][k], acc[c][1]);
        }
    }

    #pragma unroll
    for (int u = 0; u < 2; ++u) {
        int t = t0 + lane + 64 * u;
        if (t < 24000) {
            float4 vv;
            vv.x = elu(acc[0][u] + bias[co0 + 0]);
            vv.y = elu(acc[1][u] + bias[co0 + 1]);
            vv.z = elu(acc[2][u] + bias[co0 + 2]);
            vv.w = elu(acc[3][u] + bias[co0 + 3]);
            *(float4*)(H0 + ((size_t)b * 12000 + (t >> 1)) * 32 + (t & 1) * 16 + co0) = vv;
        }
    }
}

// ---------------- weight prep: 3-level bf16 A-fragments ---------------------
template<int CIN, int COUT, int TAPS>
__global__ void wprep3_kernel(const float* __restrict__ w, short* __restrict__ frag)
{
    constexpr int KC = CIN / 32;
    int co = threadIdx.x;
    if (co >= COUT) return;
    int mt = co >> 4, nc = co & 15;
    for (int kc = 0; kc < KC; ++kc)
        for (int k = 0; k < TAPS; ++k)
            #pragma unroll
            for (int lh = 0; lh < 4; ++lh) {
                bf16x8 p0, p1, p2;
                #pragma unroll
                for (int j = 0; j < 8; ++j) {
                    int ci = kc * 32 + lh * 8 + j;
                    float f = w[(size_t)co * CIN * 7 + ci * 7 + k];
                    short a, bb, c; split3(f, a, bb, c);
                    p0[j] = a; p1[j] = bb; p2[j] = c;
                }
                size_t base = ((size_t)(mt * KC + kc) * TAPS + k) * 3;
                int off = (lh * 16 + nc) * 8;
                *(bf16x8*)(frag + (base + 0) * 512 + off) = p0;
                *(bf16x8*)(frag + (base + 1) * 512 + off) = p1;
                *(bf16x8*)(frag + (base + 2) * 512 + off) = p2;
            }
}

// phase-split packing (stride-2 K=7 -> stride-1 K=4 over doubled channels)
template<int CINH, int COUT>
__global__ void wprep3_ps_kernel(const float* __restrict__ w, short* __restrict__ frag)
{
    constexpr int CIN = 2 * CINH;
    constexpr int KC  = CIN / 32;
    int co = threadIdx.x;
    if (co >= COUT) return;
    int mt = co >> 4, nc = co & 15;
    for (int kc = 0; kc < KC; ++kc)
        for (int m = 0; m < 4; ++m)
            #pragma unroll
            for (int lh = 0; lh < 4; ++lh) {
                bf16x8 p0, p1, p2;
                #pragma unroll
                for (int j = 0; j < 8; ++j) {
                    int cp = kc * 32 + lh * 8 + j;
                    float f;
                    if (cp < CINH)  f = w[(size_t)co * CINH * 7 + cp * 7 + 2 * m];
                    else if (m < 3) f = w[(size_t)co * CINH * 7 + (cp - CINH) * 7 + 2 * m + 1];
                    else            f = 0.0f;
                    short a, bb, c; split3(f, a, bb, c);
                    p0[j] = a; p1[j] = bb; p2[j] = c;
                }
                size_t base = ((size_t)(mt * KC + kc) * 4 + m) * 3;
                int off = (lh * 16 + nc) * 8;
                *(bf16x8*)(frag + (base + 0) * 512 + off) = p0;
                *(bf16x8*)(frag + (base + 1) * 512 + off) = p1;
                *(bf16x8*)(frag + (base + 2) * 512 + off) = p2;
            }
}

// ---------------- conv via 6-term split3-bf16 MFMA, t-major fp32 I/O --------
template<int S, int CIN, int COUT, int NTL, int TAPS, int PAD, int OUTMODE>
__global__ __launch_bounds__(256) void conv_mfma3_kernel(
    const float* __restrict__ Hin, const short* __restrict__ wfrag,
    const float* __restrict__ bias, float* __restrict__ Hout,
    int Lin, int Lout)
{
    constexpr int KC   = CIN / 32;
    constexpr int MT   = COUT / 16;
    constexpr int NT   = NTL * 64;
    constexpr int ROWS = (NT - 1) * S + TAPS;
    constexpr int ROWB = CIN * 2;
    constexpr int NSL  = CIN / 4;
    __shared__ __align__(16) short pl0[ROWS * CIN];
    __shared__ __align__(16) short pl1[ROWS * CIN];
    __shared__ __align__(16) short pl2[ROWS * CIN];

    int nb = blockIdx.x, b = blockIdx.y;
    int t0 = nb * NT;
    int tid = threadIdx.x, lane = tid & 63, wv = tid >> 6;
    int g0 = t0 * S - PAD;

    const float* inb = Hin + (size_t)b * Lin * CIN;
    for (int e = tid; e < ROWS * NSL; e += 256) {
        int rr = e / NSL, sl = e % NSL;
        int g = g0 + rr;
        float4 v = {0.f, 0.f, 0.f, 0.f};
        if (g >= 0 && g < Lin)
            v = *(const float4*)(inb + (size_t)g * CIN + sl * 4);
        int xr = (CIN == 64) ? (rr & 7) : ((rr >> 1) & 3);
        int byte = rr * ROWB + ((((sl >> 1) ^ xr) << 4) | ((sl & 1) << 3));
        s16x4 q0, q1, q2;
        short a0, a1, a2;
        split3(v.x, a0, a1, a2); q0[0] = a0; q1[0] = a1; q2[0] = a2;
        split3(v.y, a0, a1, a2); q0[1] = a0; q1[1] = a1; q2[1] = a2;
        split3(v.z, a0, a1, a2); q0[2] = a0; q1[2] = a1; q2[2] = a2;
        split3(v.w, a0, a1, a2); q0[3] = a0; q1[3] = a1; q2[3] = a2;
        *(s16x4*)((char*)pl0 + byte) = q0;
        *(s16x4*)((char*)pl1 + byte) = q1;
        *(s16x4*)((char*)pl2 + byte) = q2;
    }
    __syncthreads();

    f32x4 acc[NTL][MT];
    #pragma unroll
    for (int n = 0; n < NTL; ++n)
        #pragma unroll
        for (int m = 0; m < MT; ++m) acc[n][m] = (f32x4){0.f, 0.f, 0.f, 0.f};

    int ncol = lane & 15, nq = lane >> 4;

    for (int k = 0; k < TAPS; ++k) {
        #pragma unroll
        for (int kc = 0; kc < KC; ++kc) {
            int colb = (kc * 32 + nq * 8) * 2;
            bf16x8 B0[NTL], B1[NTL], B2[NTL];
            #pragma unroll
            for (int ntl = 0; ntl < NTL; ++ntl) {
                int r  = S * ((wv * NTL + ntl) * 16 + ncol) + k;
                int xr = (CIN == 64) ? (r & 7) : ((r >> 1) & 3);
                int byte = r * ROWB + (colb ^ (xr << 4));
                B0[ntl] = *(const bf16x8*)((char*)pl0 + byte);
                B1[ntl] = *(const bf16x8*)((char*)pl1 + byte);
                B2[ntl] = *(const bf16x8*)((char*)pl2 + byte);
            }
            #pragma unroll
            for (int m = 0; m < MT; ++m) {
                size_t base = ((size_t)(m * KC + kc) * TAPS + k) * 3;
                bf16x8 a0 = *(const bf16x8*)(wfrag + (base + 0) * 512 + lane * 8);
                bf16x8 a1 = *(const bf16x8*)(wfrag + (base + 1) * 512 + lane * 8);
                bf16x8 a2 = *(const bf16x8*)(wfrag + (base + 2) * 512 + lane * 8);
                #pragma unroll
                for (int ntl = 0; ntl < NTL; ++ntl) {
                    f32x4 a = acc[ntl][m];
                    a = __builtin_amdgcn_mfma_f32_16x16x32_bf16(a0, B0[ntl], a, 0, 0, 0);
                    a = __builtin_amdgcn_mfma_f32_16x16x32_bf16(a1, B0[ntl], a, 0, 0, 0);
                    a = __builtin_amdgcn_mfma_f32_16x16x32_bf16(a2, B0[ntl], a, 0, 0, 0);
                    a = __builtin_amdgcn_mfma_f32_16x16x32_bf16(a0, B1[ntl], a, 0, 0, 0);
                    a = __builtin_amdgcn_mfma_f32_16x16x32_bf16(a1, B1[ntl], a, 0, 0, 0);
                    a = __builtin_amdgcn_mfma_f32_16x16x32_bf16(a0, B2[ntl], a, 0, 0, 0);
                    acc[ntl][m] = a;
                }
            }
        }
    }

    #pragma unroll
    for (int ntl = 0; ntl < NTL; ++ntl) {
        int n = t0 + (wv * NTL + ntl) * 16 + ncol;
        if (n < Lout) {
            #pragma unroll
            for (int m = 0; m < MT; ++m) {
                int co0 = m * 16 + nq * 4;
                float4 bb = *(const float4*)(bias + co0);
                float4 vv;
                vv.x = elu(acc[ntl][m][0] + bb.x);
                vv.y = elu(acc[ntl][m][1] + bb.y);
                vv.z = elu(acc[ntl][m][2] + bb.z);
                vv.w = elu(acc[ntl][m][3] + bb.w);
                if constexpr (OUTMODE == 0) {
                    *(float4*)(Hout + ((size_t)b * Lout + n) * COUT + co0) = vv;
                } else if constexpr (OUTMODE == 1) {
                    *(float4*)(Hout + ((size_t)b * (Lout >> 1) + (n >> 1)) * (2 * COUT)
                               + (n & 1) * COUT + co0) = vv;
                } else {
                    Hout[((size_t)b * COUT + co0 + 0) * Lout + n] = vv.x;
                    Hout[((size_t)b * COUT + co0 + 1) * Lout + n] = vv.y;
                    Hout[((size_t)b * COUT + co0 + 2) * Lout + n] = vv.z;
                    Hout[((size_t)b * COUT + co0 + 3) * Lout + n] = vv.w;
                }
            }
        }
    }
}

// ---------------- VQ prep: cc (fp32, +||c||^2) + (-2c) hi/lo bf16 B-frags ---
__global__ __launch_bounds__(256) void vq_prep_kernel(
    const float* __restrict__ cbs, float* __restrict__ cc, short* __restrict__ cbf)
{
    int c = blockIdx.x * 256 + threadIdx.x;   // 0..2047
    if (c >= 2048) return;
    int cb = c >> 10, nl = c & 1023;
    const float* row = cbs + (size_t)c * 64;
    float v[64];
    float s = 0.f;
    #pragma unroll
    for (int i = 0; i < 16; ++i) {
        float4 q = ((const float4*)row)[i];
        v[4*i+0] = q.x; v[4*i+1] = q.y; v[4*i+2] = q.z; v[4*i+3] = q.w;
        s += q.x*q.x + q.y*q.y + q.z*q.z + q.w*q.w;
    }
    cc[c] = s;
    int nt = nl >> 4, nc = nl & 15;
    #pragma unroll
    for (int kc = 0; kc < 2; ++kc)
        #pragma unroll
        for (int lh = 0; lh < 4; ++lh) {
            bf16x8 ph, pl;
            #pragma unroll
            for (int j = 0; j < 8; ++j) {
                float f = -2.0f * v[kc*32 + lh*8 + j];   // exact scaling
                short h = f2bf(f);
                ph[j] = h;
                pl[j] = f2bf(f - bf2f(h));
            }
            size_t base = ((((size_t)cb*64 + nt)*2 + kc)*2);
            *(bf16x8*)(cbf + ((base + 0)*64 + (lh*16 + nc)) * 8) = ph;
            *(bf16x8*)(cbf + ((base + 1)*64 + (lh*16 + nc)) * 8) = pl;
        }
}

__global__ void zero_cnt_kernel(int* cnt) {
    if (threadIdx.x == 0 && blockIdx.x == 0) { cnt[0] = 0; cnt[1] = 0; }
}

// ---------------- VQ main: MFMA scores, unioned LDS, direct chunk copy ------
#define VQ_MARGIN 0.04f

__global__ __launch_bounds__(256)
__attribute__((amdgpu_waves_per_eu(4, 4)))
void vq_mfma_kernel(
    const float* __restrict__ z, const short* __restrict__ cbf,
    const float* __restrict__ ccg, int* __restrict__ out,
    int* __restrict__ cnt, int* __restrict__ list0, int* __restrict__ list1)
{
    // 32 KB union: z A-fragments (staging phase) then B-frag chunk (main loop)
    __shared__ __align__(16) short sbuf[16384];
    short* zf0 = sbuf;            // [8 mt][2 kc][64 lane][8] hi
    short* zf1 = sbuf + 8192;     // lo
    short* cbc = sbuf;            // chunk: [8 ntl][2 kc][2 hl][64 lane][8]

    const int T = 2000;
    int mblk = blockIdx.x;
    int cb   = blockIdx.y;
    int b    = blockIdx.z;
    int t0   = mblk * 128;
    int tid  = threadIdx.x;
    int lane = tid & 63;
    int wv   = tid >> 6;
    int* list = cb ? list1 : list0;

    // ---- stage z -> hi/lo A-fragments (b128 rows, conflict-free) ----
    const float* zb = z + ((size_t)b*128 + (size_t)cb*64) * T;
    for (int e = tid; e < 128 * 8; e += 256) {
        int tl = e & 127;
        int d0 = (e >> 7) * 8;
        int tt = t0 + tl; if (tt > T - 1) tt = T - 1;
        bf16x8 hi, lo;
        #pragma unroll
        for (int jj = 0; jj < 8; ++jj) {
            float v = zb[(size_t)(d0 + jj) * T + tt];
            short h = f2bf(v);
            hi[jj] = h;
            lo[jj] = f2bf(v - bf2f(h));
        }
        int mt = tl >> 4, kc = d0 >> 5;
        int lw = ((d0 & 31) >> 3) * 16 + (tl & 15);
        int idx = ((mt*2 + kc)*64 + lw) * 8;
        *(bf16x8*)&zf0[idx] = hi;
        *(bf16x8*)&zf1[idx] = lo;
    }
    __syncthreads();

    bf16x8 ah[2][2], al[2][2];
    #pragma unroll
    for (int mtl = 0; mtl < 2; ++mtl)
        #pragma unroll
        for (int kc = 0; kc < 2; ++kc) {
            int idx = ((((wv*2+mtl)*2 + kc)*64) + lane)*8;
            ah[mtl][kc] = *(const bf16x8*)&zf0[idx];
            al[mtl][kc] = *(const bf16x8*)&zf1[idx];
        }

    float best[2][4], second[2][4]; int bidx[2][4];
    #pragma unroll
    for (int m = 0; m < 2; ++m)
        #pragma unroll
        for (int j = 0; j < 4; ++j) { best[m][j] = 3.4e38f; second[m][j] = 3.4e38f; bidx[m][j] = 0; }

    const short* cbase = cbf + (size_t)cb * (64*2*2*64*8);
    const float* ccb   = ccg + cb * 1024;
    int c15 = lane & 15;

    for (int ch = 0; ch < 8; ++ch) {
        __syncthreads();   // all reads of sbuf (zf regs or prev chunk) done
        {
            const float4* src = (const float4*)(cbase + (size_t)ch * (8*2*2*64*8));
            float4* dst = (float4*)cbc;
            #pragma unroll
            for (int i = 0; i < 8; ++i) dst[tid + 256*i] = src[tid + 256*i];
        }
        __syncthreads();

        #pragma unroll
        for (int ntl = 0; ntl < 8; ++ntl) {
            bf16x8 b0h = *(const bf16x8*)&cbc[(((ntl*2 + 0)*2 + 0)*64 + lane)*8];
            bf16x8 b0l = *(const bf16x8*)&cbc[(((ntl*2 + 0)*2 + 1)*64 + lane)*8];
            bf16x8 b1h = *(const bf16x8*)&cbc[(((ntl*2 + 1)*2 + 0)*64 + lane)*8];
            bf16x8 b1l = *(const bf16x8*)&cbc[(((ntl*2 + 1)*2 + 1)*64 + lane)*8];
            int  code = ch*128 + ntl*16 + c15;
            float ccv = ccb[code];                 // L1-resident 8KB table
            #pragma unroll
            for (int mtl = 0; mtl < 2; ++mtl) {
                f32x4 p = {ccv, ccv, ccv, ccv};
                __builtin_amdgcn_s_setprio(1);
                p = __builtin_amdgcn_mfma_f32_16x16x32_bf16(ah[mtl][0], b0h, p, 0, 0, 0);
                p = __builtin_amdgcn_mfma_f32_16x16x32_bf16(al[mtl][0], b0h, p, 0, 0, 0);
                p = __builtin_amdgcn_mfma_f32_16x16x32_bf16(ah[mtl][0], b0l, p, 0, 0, 0);
                p = __builtin_amdgcn_mfma_f32_16x16x32_bf16(ah[mtl][1], b1h, p, 0, 0, 0);
                p = __builtin_amdgcn_mfma_f32_16x16x32_bf16(al[mtl][1], b1h, p, 0, 0, 0);
                p = __builtin_amdgcn_mfma_f32_16x16x32_bf16(ah[mtl][1], b1l, p, 0, 0, 0);
                __builtin_amdgcn_s_setprio(0);
                #pragma unroll
                for (int j = 0; j < 4; ++j) {
                    float s = p[j];
                    bool lt = s < best[mtl][j];
                    second[mtl][j] = __builtin_amdgcn_fmed3f(best[mtl][j], s, second[mtl][j]);
                    best[mtl][j]   = fminf(best[mtl][j], s);
                    bidx[mtl][j]   = lt ? code : bidx[mtl][j];
                }
            }
        }
    }

    #pragma unroll
    for (int m = 0; m < 2; ++m)
        #pragma unroll
        for (int j = 0; j < 4; ++j) {
            float bv = best[m][j], sv = second[m][j]; int bi = bidx[m][j];
            #pragma unroll
            for (int d = 1; d < 16; d <<= 1) {
                float ob = __shfl_xor(bv, d, 64);
                float os = __shfl_xor(sv, d, 64);
                int   oi = __shfl_xor(bi, d, 64);
                float loser = fmaxf(bv, ob);
                sv = fminf(fminf(sv, os), loser);
                bool sw = ob < bv;
                bv = fminf(bv, ob);
                bi = sw ? oi : bi;
            }
            if ((lane & 15) == 0) {
                int t = t0 + (wv*2 + m)*16 + (lane >> 4)*4 + j;
                if (t < T) {
                    out[((size_t)cb*64 + b)*T + t] = bi;
                    if (sv - bv < VQ_MARGIN) {
                        int pos = atomicAdd(&cnt[cb], 1);
                        list[pos] = (b << 11) | t;
                    }
                }
            }
        }
}

// ---------------- VQ rescore: 4 same-cb flags/iter share cb+w streams -------
__global__ __launch_bounds__(256) void vq_rescore_kernel(
    const float* __restrict__ H3, const float* __restrict__ wq,
    const float* __restrict__ bq, const float* __restrict__ cbs,
    const float* __restrict__ ccg, const int* __restrict__ cnt,
    const int* __restrict__ list0, const int* __restrict__ list1,
    int* __restrict__ out)
{
    const int T = 2000;
    __shared__ float hp[4][4][448];     // 28 KB
    __shared__ float zsh[4][4][64];     // 4 KB
    int tid = threadIdx.x, lane = tid & 63, wv = tid >> 6;
    int cb = blockIdx.y;
    const int* list = cb ? list1 : list0;
    int count = cnt[cb];
    int gw = blockIdx.x * 4 + wv, nw = gridDim.x * 4;

    const float* cbase = cbs + (size_t)cb * 1024 * 64;
    const float* ccb   = ccg + cb * 1024;
    int d = cb * 64 + lane;
    const float4* wp = (const float4*)(wq + (size_t)d * 448);
    float bqd = bq[d];

    for (int i0 = gw * 4; i0 < count; i0 += nw * 4) {
        int bf_[4], tf_[4];
        #pragma unroll
        for (int f = 0; f < 4; ++f) {
            int idx = i0 + f; if (idx > count - 1) idx = count - 1;
            int e = list[idx];
            bf_[f] = e >> 11; tf_[f] = e & 2047;
        }

        // stage 4x 64x7 h3 patches (lane = ci; coalesced rows)
        #pragma unroll
        for (int f = 0; f < 4; ++f) {
            size_t base = (size_t)bf_[f] * T * 64;
            #pragma unroll
            for (int kk = 0; kk < 7; ++kk) {
                int a = tf_[f] - 6 + kk;
                hp[wv][f][lane * 7 + kk] = (a >= 0) ? H3[base + (size_t)a * 64 + lane] : 0.0f;
            }
        }

        // exact fp32 conv4 for dim d; w stream shared across 4 flags
        float pa[4][4];
        #pragma unroll
        for (int f = 0; f < 4; ++f)
            #pragma unroll
            for (int j = 0; j < 4; ++j) pa[f][j] = 0.f;
        #pragma unroll 4
        for (int q = 0; q < 112; ++q) {
            float4 w4 = wp[q];
            #pragma unroll
            for (int f = 0; f < 4; ++f) {
                float4 h = *(const float4*)&hp[wv][f][4 * q];
                pa[f][0] = fmaf(w4.x, h.x, pa[f][0]);
                pa[f][1] = fmaf(w4.y, h.y, pa[f][1]);
                pa[f][2] = fmaf(w4.z, h.z, pa[f][2]);
                pa[f][3] = fmaf(w4.w, h.w, pa[f][3]);
            }
        }
        #pragma unroll
        for (int f = 0; f < 4; ++f) {
            float zv = (pa[f][0] + pa[f][1]) + (pa[f][2] + pa[f][3]) + bqd;
            zsh[wv][f][lane] = zv > 0.f ? zv : expm1f(zv);
        }

        // full exact scan; codebook row loads shared across 4 flags
        float bv[4]; int bi[4];
        #pragma unroll
        for (int f = 0; f < 4; ++f) { bv[f] = 3.4e38f; bi[f] = 0; }
        for (int ii = 0; ii < 16; ++ii) {
            int code = ii * 64 + lane;
            const float4* cp = (const float4*)(cbase + (size_t)code * 64);
            float dd[4][4];
            #pragma unroll
            for (int f = 0; f < 4; ++f)
                #pragma unroll
                for (int j = 0; j < 4; ++j) dd[f][j] = 0.f;
            #pragma unroll
            for (int q = 0; q < 16; ++q) {
                float4 cv = cp[q];
                #pragma unroll
                for (int f = 0; f < 4; ++f) {
                    float4 za = *(const float4*)&zsh[wv][f][4 * q];   // uniform broadcast
                    dd[f][0] = fmaf(za.x, cv.x, dd[f][0]);
                    dd[f][1] = fmaf(za.y, cv.y, dd[f][1]);
                    dd[f][2] = fmaf(za.z, cv.z, dd[f][2]);
                    dd[f][3] = fmaf(za.w, cv.w, dd[f][3]);
                }
            }
            float cc0 = ccb[code];
            #pragma unroll
            for (int f = 0; f < 4; ++f) {
                float s = fmaf(-2.0f, (dd[f][0] + dd[f][1]) + (dd[f][2] + dd[f][3]), cc0);
                if (s < bv[f]) { bv[f] = s; bi[f] = code; }
            }
        }
        #pragma unroll
        for (int ddp = 1; ddp < 64; ddp <<= 1) {
            #pragma unroll
            for (int f = 0; f < 4; ++f) {
                float ov = __shfl_xor(bv[f], ddp, 64);
                int   oi = __shfl_xor(bi[f], ddp, 64);
                if (ov < bv[f] || (ov == bv[f] && oi < bi[f])) { bv[f] = ov; bi[f] = oi; }
            }
        }
        if (lane == 0) {
            #pragma unroll
            for (int f = 0; f < 4; ++f)
                out[((size_t)cb * 64 + bf_[f]) * T + tf_[f]] = bi[f];
        }
    }
}

extern "C" void kernel_launch(void* const* d_in, const int* in_sizes, int n_in,
                              void* d_out, int out_size, void* d_ws, size_t ws_size,
                              hipStream_t stream)
{
    const float* x   = (const float*)d_in[0];
    const float* w0  = (const float*)d_in[1];
    const float* b0  = (const float*)d_in[2];
    const float* w1  = (const float*)d_in[3];
    const float* b1  = (const float*)d_in[4];
    const float* w2  = (const float*)d_in[5];
    const float* b2  = (const float*)d_in[6];
    const float* w3  = (const float*)d_in[7];
    const float* b3  = (const float*)d_in[8];
    const float* wq  = (const float*)d_in[9];
    const float* bq  = (const float*)d_in[10];
    const float* cbs = (const float*)d_in[11];
    int* out = (int*)d_out;

    // two 98,304,000-byte regions (proven footprint)
    char* r1 = (char*)d_ws;
    char* r2 = r1 + 98304000;
    float* H0 = (float*)r1;               // [64][12000][32] fp32 t-major (phase-split)
    float* H1 = (float*)r2;               // [64][6000][64]  (phase-split)
    float* H2 = (float*)r1;               // [64][6000][64]  (over dead H0)
    float* H3 = (float*)r2;               // [64][2000][64]  (over dead H1)
    float* z  = (float*)(r2 + 32768000);  // [64][128][2000] fp32

    // weight fragments in d_out (dead until vq_mfma rewrites it)
    short* wf1 = (short*)d_out;           // 12288 shorts
    short* wf2 = wf1 + 12288;             // 49152
    short* wf3 = wf1 + 61440;             // 86016
    short* wf4 = wf1 + 147456;            // 172032 -> ends at 319488 shorts

    // VQ prep data in r1 (free after conv3 consumes H2)
    short* cbf   = (short*)r1;
    float* cc    = (float*)(r1 + 524288);
    int*   cnt   = (int*)(r1 + 540000);
    int*   list0 = (int*)(r1 + 1000000);
    int*   list1 = (int*)(r1 + 2100000);

    // weight prep (reads inputs only)
    wprep3_ps_kernel<16, 32><<<1, 32, 0, stream>>>(w1, wf1);
    wprep3_ps_kernel<32, 64><<<1, 64, 0, stream>>>(w2, wf2);
    wprep3_kernel<64, 64, 7><<<1, 64, 0, stream>>>(w3, wf3);
    wprep3_kernel<64, 128, 7><<<1, 128, 0, stream>>>(wq, wf4);

    // conv0: x -> H0 (fp32 t-major, phase-split)
    conv0_kernel<<<dim3(188, 64), 256, 0, stream>>>(x, w0, b0, H0);
    // conv1: H0 -> H1, stride-1 K=4 over 32ch, phase-split out
    conv_mfma3_kernel<1, 32, 32, 2, 4, 3, 1><<<dim3(94, 64), 256, 0, stream>>>(
        H0, wf1, b1, H1, 12000, 12000);
    // conv2: H1 -> H2, stride-1 K=4 over 64ch, t-major out
    conv_mfma3_kernel<1, 64, 64, 2, 4, 3, 0><<<dim3(47, 64), 256, 0, stream>>>(
        H1, wf2, b2, H2, 6000, 6000);
    // conv3: H2 -> H3, stride 3, K=7, t-major out
    conv_mfma3_kernel<3, 64, 64, 1, 7, 6, 0><<<dim3(32, 64), 256, 0, stream>>>(
        H2, wf3, b3, H3, 6000, 2000);

    // VQ prep into r1 (H2 now dead)
    vq_prep_kernel<<<8, 256, 0, stream>>>(cbs, cc, cbf);
    zero_cnt_kernel<<<1, 64, 0, stream>>>(cnt);

    // conv4: H3 -> z (fp32 [co][t]), stride 1, K=7
    conv_mfma3_kernel<1, 64, 128, 2, 7, 6, 2><<<dim3(16, 64), 256, 0, stream>>>(
        H3, wf4, bq, z, 2000, 2000);

    // VQ: MFMA scores + per-cb flag lists, then 4-way shared exact rescore
    vq_mfma_kernel<<<dim3(16, 2, 64), 256, 0, stream>>>(z, cbf, cc, out, cnt, list0, list1);
    vq_rescore_kernel<<<dim3(512, 2), 256, 0, stream>>>(H3, wq, bq, cbs, cc, cnt, list0, list1, out);
}

// Round 20
// 644.789 us; speedup vs baseline: 1.1860x; 1.0007x over previous
//
#include <hip/hip_runtime.h>
#include <hip/hip_bf16.h>
#include <cstddef>

// ---------------------------------------------------------------------------
// EncoderModule: 5x causal conv1d (K=7) + ELU, then 2x VQ argmin (1024 codes, D=64)
// B=64, L=48000, strides 2,2,2,3,1; channels 1->16->32->64->64->128
// Output: int32 indices, shape (2, 64, 2000)
//
// Inter-layer tensors: fp32, t-major [t][ci]. Convs 1-4: 6-term split3-bf16
// MFMA (round-14 numerics, passed absmax 0).
// VQ: codebook pre-scaled by -2, ||c||^2 folded into MFMA accumulator init,
// med3 best/second; 32KB LDS = 2x16KB double-buffered 64-code chunks with
// issue-early/write-late staging (one barrier per chunk, load latency hidden
// under the MFMA block); waves_per_eu(4,4) (r16/r17 spill lesson).
// gap < 0.04 -> flag. Rescore: 4 same-cb flags/iter share cb+w streams.
// ---------------------------------------------------------------------------

using bf16x8 = __attribute__((ext_vector_type(8))) short;
using s16x4  = __attribute__((ext_vector_type(4))) short;
using f32x4  = __attribute__((ext_vector_type(4))) float;

static __device__ __forceinline__ short f2bf(float f) {
    __hip_bfloat16 h = __float2bfloat16(f);   // RNE
    union { __hip_bfloat16 h; short s; } u; u.h = h;
    return u.s;
}
static __device__ __forceinline__ float bf2f(short s) {
    union { unsigned u; float f; } v;
    v.u = ((unsigned)(unsigned short)s) << 16;
    return v.f;
}
static __device__ __forceinline__ void split3(float v, short& s0, short& s1, short& s2) {
    s0 = f2bf(v);  float r1 = v  - bf2f(s0);   // exact
    s1 = f2bf(r1); float r2 = r1 - bf2f(s1);   // exact
    s2 = f2bf(r2);                             // residual ~2^-24 |v|
}
static __device__ __forceinline__ float elu(float v) {
    return v > 0.0f ? v : expm1f(v);
}

// ---------------- conv0: fp32 VALU, t-major phase-split store ---------------
__global__ __launch_bounds__(256) void conv0_kernel(
    const float* __restrict__ x, const float* __restrict__ w,
    const float* __restrict__ bias, float* __restrict__ H0)
{
    __shared__ float xs[261];                  // (128-1)*2+7
    int tb = blockIdx.x, b = blockIdx.y;
    int t0 = tb * 128;
    int tid = threadIdx.x, lane = tid & 63;
    int wv = __builtin_amdgcn_readfirstlane(tid >> 6);

    const float* xb = x + (size_t)b * 48000;
    int g0 = t0 * 2 - 6;
    for (int i = tid; i < 261; i += 256) {
        int gx = g0 + i;
        xs[i] = (gx >= 0 && gx < 48000) ? xb[gx] : 0.0f;
    }
    __syncthreads();

    int co0 = wv * 4;
    float acc[4][2];
    #pragma unroll
    for (int c = 0; c < 4; ++c) { acc[c][0] = 0.f; acc[c][1] = 0.f; }

    float xw[2][7];
    #pragma unroll
    for (int u = 0; u < 2; ++u)
        #pragma unroll
        for (int k = 0; k < 7; ++k)
            xw[u][k] = xs[(lane + 64 * u) * 2 + k];
    #pragma unroll
    for (int c = 0; c < 4; ++c) {
        const float* wp = w + (size_t)(co0 + c) * 7;   // s_load
        #pragma unroll
        for (int k = 0; k < 7; ++k) {
            float wk = wp[k];
            acc[c][0] = fmaf(wk, xw[0][k], acc[c][0]);
            acc[c][1] = fmaf(wk, xw[1][k], acc[c][1]);
        }
    }

    #pragma unroll
    for (int u = 0; u < 2; ++u) {
        int t = t0 + lane + 64 * u;
        if (t < 24000) {
            float4 vv;
            vv.x = elu(acc[0][u] + bias[co0 + 0]);
            vv.y = elu(acc[1][u] + bias[co0 + 1]);
            vv.z = elu(acc[2][u] + bias[co0 + 2]);
            vv.w = elu(acc[3][u] + bias[co0 + 3]);
            *(float4*)(H0 + ((size_t)b * 12000 + (t >> 1)) * 32 + (t & 1) * 16 + co0) = vv;
        }
    }
}

// ---------------- weight prep: 3-level bf16 A-fragments ---------------------
template<int CIN, int COUT, int TAPS>
__global__ void wprep3_kernel(const float* __restrict__ w, short* __restrict__ frag)
{
    constexpr int KC = CIN / 32;
    int co = threadIdx.x;
    if (co >= COUT) return;
    int mt = co >> 4, nc = co & 15;
    for (int kc = 0; kc < KC; ++kc)
        for (int k = 0; k < TAPS; ++k)
            #pragma unroll
            for (int lh = 0; lh < 4; ++lh) {
                bf16x8 p0, p1, p2;
                #pragma unroll
                for (int j = 0; j < 8; ++j) {
                    int ci = kc * 32 + lh * 8 + j;
                    float f = w[(size_t)co * CIN * 7 + ci * 7 + k];
                    short a, bb, c; split3(f, a, bb, c);
                    p0[j] = a; p1[j] = bb; p2[j] = c;
                }
                size_t base = ((size_t)(mt * KC + kc) * TAPS + k) * 3;
                int off = (lh * 16 + nc) * 8;
                *(bf16x8*)(frag + (base + 0) * 512 + off) = p0;
                *(bf16x8*)(frag + (base + 1) * 512 + off) = p1;
                *(bf16x8*)(frag + (base + 2) * 512 + off) = p2;
            }
}

// phase-split packing (stride-2 K=7 -> stride-1 K=4 over doubled channels)
template<int CINH, int COUT>
__global__ void wprep3_ps_kernel(const float* __restrict__ w, short* __restrict__ frag)
{
    constexpr int CIN = 2 * CINH;
    constexpr int KC  = CIN / 32;
    int co = threadIdx.x;
    if (co >= COUT) return;
    int mt = co >> 4, nc = co & 15;
    for (int kc = 0; kc < KC; ++kc)
        for (int m = 0; m < 4; ++m)
            #pragma unroll
            for (int lh = 0; lh < 4; ++lh) {
                bf16x8 p0, p1, p2;
                #pragma unroll
                for (int j = 0; j < 8; ++j) {
                    int cp = kc * 32 + lh * 8 + j;
                    float f;
                    if (cp < CINH)  f = w[(size_t)co * CINH * 7 + cp * 7 + 2 * m];
                    else if (m < 3) f = w[(size_t)co * CINH * 7 + (cp - CINH) * 7 + 2 * m + 1];
                    else            f = 0.0f;
                    short a, bb, c; split3(f, a, bb, c);
                    p0[j] = a; p1[j] = bb; p2[j] = c;
                }
                size_t base = ((size_t)(mt * KC + kc) * 4 + m) * 3;
                int off = (lh * 16 + nc) * 8;
                *(bf16x8*)(frag + (base + 0) * 512 + off) = p0;
                *(bf16x8*)(frag + (base + 1) * 512 + off) = p1;
                *(bf16x8*)(frag + (base + 2) * 512 + off) = p2;
            }
}

// ---------------- conv via 6-term split3-bf16 MFMA, t-major fp32 I/O --------
template<int S, int CIN, int COUT, int NTL, int TAPS, int PAD, int OUTMODE>
__global__ __launch_bounds__(256) void conv_mfma3_kernel(
    const float* __restrict__ Hin, const short* __restrict__ wfrag,
    const float* __restrict__ bias, float* __restrict__ Hout,
    int Lin, int Lout)
{
    constexpr int KC   = CIN / 32;
    constexpr int MT   = COUT / 16;
    constexpr int NT   = NTL * 64;
    constexpr int ROWS = (NT - 1) * S + TAPS;
    constexpr int ROWB = CIN * 2;
    constexpr int NSL  = CIN / 4;
    __shared__ __align__(16) short pl0[ROWS * CIN];
    __shared__ __align__(16) short pl1[ROWS * CIN];
    __shared__ __align__(16) short pl2[ROWS * CIN];

    int nb = blockIdx.x, b = blockIdx.y;
    int t0 = nb * NT;
    int tid = threadIdx.x, lane = tid & 63, wv = tid >> 6;
    int g0 = t0 * S - PAD;

    const float* inb = Hin + (size_t)b * Lin * CIN;
    for (int e = tid; e < ROWS * NSL; e += 256) {
        int rr = e / NSL, sl = e % NSL;
        int g = g0 + rr;
        float4 v = {0.f, 0.f, 0.f, 0.f};
        if (g >= 0 && g < Lin)
            v = *(const float4*)(inb + (size_t)g * CIN + sl * 4);
        int xr = (CIN == 64) ? (rr & 7) : ((rr >> 1) & 3);
        int byte = rr * ROWB + ((((sl >> 1) ^ xr) << 4) | ((sl & 1) << 3));
        s16x4 q0, q1, q2;
        short a0, a1, a2;
        split3(v.x, a0, a1, a2); q0[0] = a0; q1[0] = a1; q2[0] = a2;
        split3(v.y, a0, a1, a2); q0[1] = a0; q1[1] = a1; q2[1] = a2;
        split3(v.z, a0, a1, a2); q0[2] = a0; q1[2] = a1; q2[2] = a2;
        split3(v.w, a0, a1, a2); q0[3] = a0; q1[3] = a1; q2[3] = a2;
        *(s16x4*)((char*)pl0 + byte) = q0;
        *(s16x4*)((char*)pl1 + byte) = q1;
        *(s16x4*)((char*)pl2 + byte) = q2;
    }
    __syncthreads();

    f32x4 acc[NTL][MT];
    #pragma unroll
    for (int n = 0; n < NTL; ++n)
        #pragma unroll
        for (int m = 0; m < MT; ++m) acc[n][m] = (f32x4){0.f, 0.f, 0.f, 0.f};

    int ncol = lane & 15, nq = lane >> 4;

    for (int k = 0; k < TAPS; ++k) {
        #pragma unroll
        for (int kc = 0; kc < KC; ++kc) {
            int colb = (kc * 32 + nq * 8) * 2;
            bf16x8 B0[NTL], B1[NTL], B2[NTL];
            #pragma unroll
            for (int ntl = 0; ntl < NTL; ++ntl) {
                int r  = S * ((wv * NTL + ntl) * 16 + ncol) + k;
                int xr = (CIN == 64) ? (r & 7) : ((r >> 1) & 3);
                int byte = r * ROWB + (colb ^ (xr << 4));
                B0[ntl] = *(const bf16x8*)((char*)pl0 + byte);
                B1[ntl] = *(const bf16x8*)((char*)pl1 + byte);
                B2[ntl] = *(const bf16x8*)((char*)pl2 + byte);
            }
            #pragma unroll
            for (int m = 0; m < MT; ++m) {
                size_t base = ((size_t)(m * KC + kc) * TAPS + k) * 3;
                bf16x8 a0 = *(const bf16x8*)(wfrag + (base + 0) * 512 + lane * 8);
                bf16x8 a1 = *(const bf16x8*)(wfrag + (base + 1) * 512 + lane * 8);
                bf16x8 a2 = *(const bf16x8*)(wfrag + (base + 2) * 512 + lane * 8);
                #pragma unroll
                for (int ntl = 0; ntl < NTL; ++ntl) {
                    f32x4 a = acc[ntl][m];
                    a = __builtin_amdgcn_mfma_f32_16x16x32_bf16(a0, B0[ntl], a, 0, 0, 0);
                    a = __builtin_amdgcn_mfma_f32_16x16x32_bf16(a1, B0[ntl], a, 0, 0, 0);
                    a = __builtin_amdgcn_mfma_f32_16x16x32_bf16(a2, B0[ntl], a, 0, 0, 0);
                    a = __builtin_amdgcn_mfma_f32_16x16x32_bf16(a0, B1[ntl], a, 0, 0, 0);
                    a = __builtin_amdgcn_mfma_f32_16x16x32_bf16(a1, B1[ntl], a, 0, 0, 0);
                    a = __builtin_amdgcn_mfma_f32_16x16x32_bf16(a0, B2[ntl], a, 0, 0, 0);
                    acc[ntl][m] = a;
                }
            }
        }
    }

    #pragma unroll
    for (int ntl = 0; ntl < NTL; ++ntl) {
        int n = t0 + (wv * NTL + ntl) * 16 + ncol;
        if (n < Lout) {
            #pragma unroll
            for (int m = 0; m < MT; ++m) {
                int co0 = m * 16 + nq * 4;
                float4 bb = *(const float4*)(bias + co0);
                float4 vv;
                vv.x = elu(acc[ntl][m][0] + bb.x);
                vv.y = elu(acc[ntl][m][1] + bb.y);
                vv.z = elu(acc[ntl][m][2] + bb.z);
                vv.w = elu(acc[ntl][m][3] + bb.w);
                if constexpr (OUTMODE == 0) {
                    *(float4*)(Hout + ((size_t)b * Lout + n) * COUT + co0) = vv;
                } else if constexpr (OUTMODE == 1) {
                    *(float4*)(Hout + ((size_t)b * (Lout >> 1) + (n >> 1)) * (2 * COUT)
                               + (n & 1) * COUT + co0) = vv;
                } else {
                    Hout[((size_t)b * COUT + co0 + 0) * Lout + n] = vv.x;
                    Hout[((size_t)b * COUT + co0 + 1) * Lout + n] = vv.y;
                    Hout[((size_t)b * COUT + co0 + 2) * Lout + n] = vv.z;
                    Hout[((size_t)b * COUT + co0 + 3) * Lout + n] = vv.w;
                }
            }
        }
    }
}

// ---------------- VQ prep: cc (fp32, +||c||^2) + (-2c) hi/lo bf16 B-frags ---
__global__ __launch_bounds__(256) void vq_prep_kernel(
    const float* __restrict__ cbs, float* __restrict__ cc, short* __restrict__ cbf)
{
    int c = blockIdx.x * 256 + threadIdx.x;   // 0..2047
    if (c >= 2048) return;
    int cb = c >> 10, nl = c & 1023;
    const float* row = cbs + (size_t)c * 64;
    float v[64];
    float s = 0.f;
    #pragma unroll
    for (int i = 0; i < 16; ++i) {
        float4 q = ((const float4*)row)[i];
        v[4*i+0] = q.x; v[4*i+1] = q.y; v[4*i+2] = q.z; v[4*i+3] = q.w;
        s += q.x*q.x + q.y*q.y + q.z*q.z + q.w*q.w;
    }
    cc[c] = s;
    int nt = nl >> 4, nc = nl & 15;
    #pragma unroll
    for (int kc = 0; kc < 2; ++kc)
        #pragma unroll
        for (int lh = 0; lh < 4; ++lh) {
            bf16x8 ph, pl;
            #pragma unroll
            for (int j = 0; j < 8; ++j) {
                float f = -2.0f * v[kc*32 + lh*8 + j];   // exact scaling
                short h = f2bf(f);
                ph[j] = h;
                pl[j] = f2bf(f - bf2f(h));
            }
            size_t base = ((((size_t)cb*64 + nt)*2 + kc)*2);
            *(bf16x8*)(cbf + ((base + 0)*64 + (lh*16 + nc)) * 8) = ph;
            *(bf16x8*)(cbf + ((base + 1)*64 + (lh*16 + nc)) * 8) = pl;
        }
}

__global__ void zero_cnt_kernel(int* cnt) {
    if (threadIdx.x == 0 && blockIdx.x == 0) { cnt[0] = 0; cnt[1] = 0; }
}

// ---------------- VQ main: MFMA scores, double-buffered 64-code chunks ------
#define VQ_MARGIN 0.04f

__global__ __launch_bounds__(256)
__attribute__((amdgpu_waves_per_eu(4, 4)))
void vq_mfma_kernel(
    const float* __restrict__ z, const short* __restrict__ cbf,
    const float* __restrict__ ccg, int* __restrict__ out,
    int* __restrict__ cnt, int* __restrict__ list0, int* __restrict__ list1)
{
    // 32 KB: z A-fragments during staging, then 2x16KB chunk double-buffer
    __shared__ __align__(16) short sbuf[16384];
    short* zf0 = sbuf;            // [8 mt][2 kc][64 lane][8] hi (16 KB)
    short* zf1 = sbuf + 8192;     // lo (16 KB)

    const int T = 2000;
    int mblk = blockIdx.x;
    int cb   = blockIdx.y;
    int b    = blockIdx.z;
    int t0   = mblk * 128;
    int tid  = threadIdx.x;
    int lane = tid & 63;
    int wv   = tid >> 6;
    int* list = cb ? list1 : list0;

    // ---- stage z -> hi/lo A-fragments (b128 rows, conflict-free) ----
    const float* zb = z + ((size_t)b*128 + (size_t)cb*64) * T;
    for (int e = tid; e < 128 * 8; e += 256) {
        int tl = e & 127;
        int d0 = (e >> 7) * 8;
        int tt = t0 + tl; if (tt > T - 1) tt = T - 1;
        bf16x8 hi, lo;
        #pragma unroll
        for (int jj = 0; jj < 8; ++jj) {
            float v = zb[(size_t)(d0 + jj) * T + tt];
            short h = f2bf(v);
            hi[jj] = h;
            lo[jj] = f2bf(v - bf2f(h));
        }
        int mt = tl >> 4, kc = d0 >> 5;
        int lw = ((d0 & 31) >> 3) * 16 + (tl & 15);
        int idx = ((mt*2 + kc)*64 + lw) * 8;
        *(bf16x8*)&zf0[idx] = hi;
        *(bf16x8*)&zf1[idx] = lo;
    }
    __syncthreads();

    bf16x8 ah[2][2], al[2][2];
    #pragma unroll
    for (int mtl = 0; mtl < 2; ++mtl)
        #pragma unroll
        for (int kc = 0; kc < 2; ++kc) {
            int idx = ((((wv*2+mtl)*2 + kc)*64) + lane)*8;
            ah[mtl][kc] = *(const bf16x8*)&zf0[idx];
            al[mtl][kc] = *(const bf16x8*)&zf1[idx];
        }
    __syncthreads();   // zf reads complete; sbuf is now the chunk double-buffer

    float best[2][4], second[2][4]; int bidx[2][4];
    #pragma unroll
    for (int m = 0; m < 2; ++m)
        #pragma unroll
        for (int j = 0; j < 4; ++j) { best[m][j] = 3.4e38f; second[m][j] = 3.4e38f; bidx[m][j] = 0; }

    const short* cbase = cbf + (size_t)cb * (64*2*2*64*8);
    const float* ccb   = ccg + cb * 1024;
    int c15 = lane & 15;

    // chunk ch (0..15): 64 codes, 16 KB at cbase + ch*8192 shorts.
    // buffer halves: sbuf[0..8192) and sbuf[8192..16384)
    {   // synchronous copy of chunk 0 into buf 0
        const float4* src = (const float4*)cbase;
        float4* dst = (float4*)sbuf;
        #pragma unroll
        for (int i = 0; i < 4; ++i) dst[tid + 256*i] = src[tid + 256*i];
    }
    __syncthreads();

    for (int ch = 0; ch < 16; ++ch) {
        short* cur = sbuf + (ch & 1) * 8192;
        short* nxt = sbuf + ((ch + 1) & 1) * 8192;
        float4 pre0, pre1, pre2, pre3;
        if (ch < 15) {   // issue-early: loads for next chunk
            const float4* src = (const float4*)(cbase + (size_t)(ch + 1) * 8192);
            pre0 = src[tid];       pre1 = src[tid + 256];
            pre2 = src[tid + 512]; pre3 = src[tid + 768];
        }

        #pragma unroll
        for (int ntl = 0; ntl < 4; ++ntl) {
            bf16x8 b0h = *(const bf16x8*)&cur[(((ntl*2 + 0)*2 + 0)*64 + lane)*8];
            bf16x8 b0l = *(const bf16x8*)&cur[(((ntl*2 + 0)*2 + 1)*64 + lane)*8];
            bf16x8 b1h = *(const bf16x8*)&cur[(((ntl*2 + 1)*2 + 0)*64 + lane)*8];
            bf16x8 b1l = *(const bf16x8*)&cur[(((ntl*2 + 1)*2 + 1)*64 + lane)*8];
            int  code = ch*64 + ntl*16 + c15;
            float ccv = ccb[code];                 // L1-resident 8KB table
            #pragma unroll
            for (int mtl = 0; mtl < 2; ++mtl) {
                f32x4 p = {ccv, ccv, ccv, ccv};
                __builtin_amdgcn_s_setprio(1);
                p = __builtin_amdgcn_mfma_f32_16x16x32_bf16(ah[mtl][0], b0h, p, 0, 0, 0);
                p = __builtin_amdgcn_mfma_f32_16x16x32_bf16(al[mtl][0], b0h, p, 0, 0, 0);
                p = __builtin_amdgcn_mfma_f32_16x16x32_bf16(ah[mtl][0], b0l, p, 0, 0, 0);
                p = __builtin_amdgcn_mfma_f32_16x16x32_bf16(ah[mtl][1], b1h, p, 0, 0, 0);
                p = __builtin_amdgcn_mfma_f32_16x16x32_bf16(al[mtl][1], b1h, p, 0, 0, 0);
                p = __builtin_amdgcn_mfma_f32_16x16x32_bf16(ah[mtl][1], b1l, p, 0, 0, 0);
                __builtin_amdgcn_s_setprio(0);
                #pragma unroll
                for (int j = 0; j < 4; ++j) {
                    float s = p[j];
                    bool lt = s < best[mtl][j];
                    second[mtl][j] = __builtin_amdgcn_fmed3f(best[mtl][j], s, second[mtl][j]);
                    best[mtl][j]   = fminf(best[mtl][j], s);
                    bidx[mtl][j]   = lt ? code : bidx[mtl][j];
                }
            }
        }

        if (ch < 15) {   // write-late into the other buffer
            float4* dst = (float4*)nxt;
            dst[tid]       = pre0;  dst[tid + 256] = pre1;
            dst[tid + 512] = pre2;  dst[tid + 768] = pre3;
        }
        __syncthreads();  // writes to nxt visible; reads of cur done
    }

    #pragma unroll
    for (int m = 0; m < 2; ++m)
        #pragma unroll
        for (int j = 0; j < 4; ++j) {
            float bv = best[m][j], sv = second[m][j]; int bi = bidx[m][j];
            #pragma unroll
            for (int d = 1; d < 16; d <<= 1) {
                float ob = __shfl_xor(bv, d, 64);
                float os = __shfl_xor(sv, d, 64);
                int   oi = __shfl_xor(bi, d, 64);
                float loser = fmaxf(bv, ob);
                sv = fminf(fminf(sv, os), loser);
                bool sw = ob < bv;
                bv = fminf(bv, ob);
                bi = sw ? oi : bi;
            }
            if ((lane & 15) == 0) {
                int t = t0 + (wv*2 + m)*16 + (lane >> 4)*4 + j;
                if (t < T) {
                    out[((size_t)cb*64 + b)*T + t] = bi;
                    if (sv - bv < VQ_MARGIN) {
                        int pos = atomicAdd(&cnt[cb], 1);
                        list[pos] = (b << 11) | t;
                    }
                }
            }
        }
}

// ---------------- VQ rescore: 4 same-cb flags/iter share cb+w streams -------
__global__ __launch_bounds__(256) void vq_rescore_kernel(
    const float* __restrict__ H3, const float* __restrict__ wq,
    const float* __restrict__ bq, const float* __restrict__ cbs,
    const float* __restrict__ ccg, const int* __restrict__ cnt,
    const int* __restrict__ list0, const int* __restrict__ list1,
    int* __restrict__ out)
{
    const int T = 2000;
    __shared__ float hp[4][4][448];     // 28 KB
    __shared__ float zsh[4][4][64];     // 4 KB
    int tid = threadIdx.x, lane = tid & 63, wv = tid >> 6;
    int cb = blockIdx.y;
    const int* list = cb ? list1 : list0;
    int count = cnt[cb];
    int gw = blockIdx.x * 4 + wv, nw = gridDim.x * 4;

    const float* cbase = cbs + (size_t)cb * 1024 * 64;
    const float* ccb   = ccg + cb * 1024;
    int d = cb * 64 + lane;
    const float4* wp = (const float4*)(wq + (size_t)d * 448);
    float bqd = bq[d];

    for (int i0 = gw * 4; i0 < count; i0 += nw * 4) {
        int bf_[4], tf_[4];
        #pragma unroll
        for (int f = 0; f < 4; ++f) {
            int idx = i0 + f; if (idx > count - 1) idx = count - 1;
            int e = list[idx];
            bf_[f] = e >> 11; tf_[f] = e & 2047;
        }

        #pragma unroll
        for (int f = 0; f < 4; ++f) {
            size_t base = (size_t)bf_[f] * T * 64;
            #pragma unroll
            for (int kk = 0; kk < 7; ++kk) {
                int a = tf_[f] - 6 + kk;
                hp[wv][f][lane * 7 + kk] = (a >= 0) ? H3[base + (size_t)a * 64 + lane] : 0.0f;
            }
        }

        float pa[4][4];
        #pragma unroll
        for (int f = 0; f < 4; ++f)
            #pragma unroll
            for (int j = 0; j < 4; ++j) pa[f][j] = 0.f;
        #pragma unroll 4
        for (int q = 0; q < 112; ++q) {
            float4 w4 = wp[q];
            #pragma unroll
            for (int f = 0; f < 4; ++f) {
                float4 h = *(const float4*)&hp[wv][f][4 * q];
                pa[f][0] = fmaf(w4.x, h.x, pa[f][0]);
                pa[f][1] = fmaf(w4.y, h.y, pa[f][1]);
                pa[f][2] = fmaf(w4.z, h.z, pa[f][2]);
                pa[f][3] = fmaf(w4.w, h.w, pa[f][3]);
            }
        }
        #pragma unroll
        for (int f = 0; f < 4; ++f) {
            float zv = (pa[f][0] + pa[f][1]) + (pa[f][2] + pa[f][3]) + bqd;
            zsh[wv][f][lane] = zv > 0.f ? zv : expm1f(zv);
        }

        float bv[4]; int bi[4];
        #pragma unroll
        for (int f = 0; f < 4; ++f) { bv[f] = 3.4e38f; bi[f] = 0; }
        for (int ii = 0; ii < 16; ++ii) {
            int code = ii * 64 + lane;
            const float4* cp = (const float4*)(cbase + (size_t)code * 64);
            float dd[4][4];
            #pragma unroll
            for (int f = 0; f < 4; ++f)
                #pragma unroll
                for (int j = 0; j < 4; ++j) dd[f][j] = 0.f;
            #pragma unroll
            for (int q = 0; q < 16; ++q) {
                float4 cv = cp[q];
                #pragma unroll
                for (int f = 0; f < 4; ++f) {
                    float4 za = *(const float4*)&zsh[wv][f][4 * q];   // uniform broadcast
                    dd[f][0] = fmaf(za.x, cv.x, dd[f][0]);
                    dd[f][1] = fmaf(za.y, cv.y, dd[f][1]);
                    dd[f][2] = fmaf(za.z, cv.z, dd[f][2]);
                    dd[f][3] = fmaf(za.w, cv.w, dd[f][3]);
                }
            }
            float cc0 = ccb[code];
            #pragma unroll
            for (int f = 0; f < 4; ++f) {
                float s = fmaf(-2.0f, (dd[f][0] + dd[f][1]) + (dd[f][2] + dd[f][3]), cc0);
                if (s < bv[f]) { bv[f] = s; bi[f] = code; }
            }
        }
        #pragma unroll
        for (int ddp = 1; ddp < 64; ddp <<= 1) {
            #pragma unroll
            for (int f = 0; f < 4; ++f) {
                float ov = __shfl_xor(bv[f], ddp, 64);
                int   oi = __shfl_xor(bi[f], ddp, 64);
                if (ov < bv[f] || (ov == bv[f] && oi < bi[f])) { bv[f] = ov; bi[f] = oi; }
            }
        }
        if (lane == 0) {
            #pragma unroll
            for (int f = 0; f < 4; ++f)
                out[((size_t)cb * 64 + bf_[f]) * T + tf_[f]] = bi[f];
        }
    }
}

extern "C" void kernel_launch(void* const* d_in, const int* in_sizes, int n_in,
                              void* d_out, int out_size, void* d_ws, size_t ws_size,
                              hipStream_t stream)
{
    const float* x   = (const float*)d_in[0];
    const float* w0  = (const float*)d_in[1];
    const float* b0  = (const float*)d_in[2];
    const float* w1  = (const float*)d_in[3];
    const float* b1  = (const float*)d_in[4];
    const float* w2  = (const float*)d_in[5];
    const float* b2  = (const float*)d_in[6];
    const float* w3  = (const float*)d_in[7];
    const float* b3  = (const float*)d_in[8];
    const float* wq  = (const float*)d_in[9];
    const float* bq  = (const float*)d_in[10];
    const float* cbs = (const float*)d_in[11];
    int* out = (int*)d_out;

    // two 98,304,000-byte regions (proven footprint)
    char* r1 = (char*)d_ws;
    char* r2 = r1 + 98304000;
    float* H0 = (float*)r1;               // [64][12000][32] fp32 t-major (phase-split)
    float* H1 = (float*)r2;               // [64][6000][64]  (phase-split)
    float* H2 = (float*)r1;               // [64][6000][64]  (over dead H0)
    float* H3 = (float*)r2;               // [64][2000][64]  (over dead H1)
    float* z  = (float*)(r2 + 32768000);  // [64][128][2000] fp32

    // weight fragments in d_out (dead until vq_mfma rewrites it)
    short* wf1 = (short*)d_out;           // 12288 shorts
    short* wf2 = wf1 + 12288;             // 49152
    short* wf3 = wf1 + 61440;             // 86016
    short* wf4 = wf1 + 147456;            // 172032 -> ends at 319488 shorts

    // VQ prep data in r1 (free after conv3 consumes H2)
    short* cbf   = (short*)r1;
    float* cc    = (float*)(r1 + 524288);
    int*   cnt   = (int*)(r1 + 540000);
    int*   list0 = (int*)(r1 + 1000000);
    int*   list1 = (int*)(r1 + 2100000);

    // weight prep (reads inputs only)
    wprep3_ps_kernel<16, 32><<<1, 32, 0, stream>>>(w1, wf1);
    wprep3_ps_kernel<32, 64><<<1, 64, 0, stream>>>(w2, wf2);
    wprep3_kernel<64, 64, 7><<<1, 64, 0, stream>>>(w3, wf3);
    wprep3_kernel<64, 128, 7><<<1, 128, 0, stream>>>(wq, wf4);

    // conv0: x -> H0 (fp32 t-major, phase-split)
    conv0_kernel<<<dim3(188, 64), 256, 0, stream>>>(x, w0, b0, H0);
    // conv1: H0 -> H1, stride-1 K=4 over 32ch, phase-split out
    conv_mfma3_kernel<1, 32, 32, 2, 4, 3, 1><<<dim3(94, 64), 256, 0, stream>>>(
        H0, wf1, b1, H1, 12000, 12000);
    // conv2: H1 -> H2, stride-1 K=4 over 64ch, t-major out
    conv_mfma3_kernel<1, 64, 64, 2, 4, 3, 0><<<dim3(47, 64), 256, 0, stream>>>(
        H1, wf2, b2, H2, 6000, 6000);
    // conv3: H2 -> H3, stride 3, K=7, t-major out
    conv_mfma3_kernel<3, 64, 64, 1, 7, 6, 0><<<dim3(32, 64), 256, 0, stream>>>(
        H2, wf3, b3, H3, 6000, 2000);

    // VQ prep into r1 (H2 now dead)
    vq_prep_kernel<<<8, 256, 0, stream>>>(cbs, cc, cbf);
    zero_cnt_kernel<<<1, 64, 0, stream>>>(cnt);

    // conv4: H3 -> z (fp32 [co][t]), stride 1, K=7
    conv_mfma3_kernel<1, 64, 128, 2, 7, 6, 2><<<dim3(16, 64), 256, 0, stream>>>(
        H3, wf4, bq, z, 2000, 2000);

    // VQ: MFMA scores + per-cb flag lists, then 4-way shared exact rescore
    vq_mfma_kernel<<<dim3(16, 2, 64), 256, 0, stream>>>(z, cbf, cc, out, cnt, list0, list1);
    vq_rescore_kernel<<<dim3(512, 2), 256, 0, stream>>>(H3, wq, bq, cbs, cc, cnt, list0, list1, out);
}

// Round 21
// 637.161 us; speedup vs baseline: 1.2002x; 1.0120x over previous
//
#include <hip/hip_runtime.h>
#include <hip/hip_bf16.h>
#include <cstddef>

// ---------------------------------------------------------------------------
// EncoderModule: 5x causal conv1d (K=7) + ELU, then 2x VQ argmin (1024 codes, D=64)
// B=64, L=48000, strides 2,2,2,3,1; channels 1->16->32->64->64->128
// Output: int32 indices, shape (2, 64, 2000)
//
// conv0 FUSED into conv1 (r21): the fused kernel recomputes the H0 tile from x
// bit-identically (same FMA order / elu / zero-fill), split3's into the same
// swizzled LDS planes, then runs conv1's verified MFMA body — eliminating the
// 196.6MB H0 round-trip and a dispatch.
// convs 2-4: 6-term split3-bf16 MFMA, fp32 t-major I/O (round-14 numerics).
// VQ: -2c codebook, ||c||^2 in accumulator init, med3 best/second, 2x16KB
// double-buffered chunks, waves_per_eu(4,4). gap<0.04 -> flag; 4-way rescore.
// ---------------------------------------------------------------------------

using bf16x8 = __attribute__((ext_vector_type(8))) short;
using s16x4  = __attribute__((ext_vector_type(4))) short;
using f32x4  = __attribute__((ext_vector_type(4))) float;

static __device__ __forceinline__ short f2bf(float f) {
    __hip_bfloat16 h = __float2bfloat16(f);   // RNE
    union { __hip_bfloat16 h; short s; } u; u.h = h;
    return u.s;
}
static __device__ __forceinline__ float bf2f(short s) {
    union { unsigned u; float f; } v;
    v.u = ((unsigned)(unsigned short)s) << 16;
    return v.f;
}
static __device__ __forceinline__ void split3(float v, short& s0, short& s1, short& s2) {
    s0 = f2bf(v);  float r1 = v  - bf2f(s0);   // exact
    s1 = f2bf(r1); float r2 = r1 - bf2f(s1);   // exact
    s2 = f2bf(r2);                             // residual ~2^-24 |v|
}
static __device__ __forceinline__ float elu(float v) {
    return v > 0.0f ? v : expm1f(v);
}

// ---------------- fused conv0+conv1 -----------------------------------------
// Computes H0 rows (phase-split, bit-identical to the old conv0) directly into
// the split3 LDS planes, then conv1 = stride-1 K=4 MFMA over 32ch, OUTMODE=1.
__global__ __launch_bounds__(256) void conv01_kernel(
    const float* __restrict__ x, const float* __restrict__ w0,
    const float* __restrict__ b0, const short* __restrict__ wfrag,
    const float* __restrict__ bias, float* __restrict__ Hout)
{
    constexpr int CIN = 32, COUT = 32, NTL = 2, TAPS = 4, S = 1;
    constexpr int KC = 1, MT = 2, NT = 128, ROWS = 131, ROWB = 64;
    constexpr int Lin = 12000, Lout = 12000;
    __shared__ __align__(16) short pl0[ROWS * CIN];
    __shared__ __align__(16) short pl1[ROWS * CIN];
    __shared__ __align__(16) short pl2[ROWS * CIN];
    __shared__ float xs[536];

    int nb = blockIdx.x, b = blockIdx.y;
    int t0 = nb * NT;
    int tid = threadIdx.x, lane = tid & 63, wv = tid >> 6;
    int g0 = t0 - 3;                      // first H0 row (u) in the tile

    // stage x segment covering conv0 for u in [g0, g0+131): x[4*g0-6 .. 4*g0+528]
    const float* xb = x + (size_t)b * 48000;
    int xbase = 4 * g0 - 6;
    for (int i = tid; i < 529; i += 256) {
        int g = xbase + i;
        xs[i] = (g >= 0 && g < 48000) ? xb[g] : 0.0f;
    }
    __syncthreads();

    // compute H0[u][ch] (ch = co + 16*(t&1), t = 2u+ph) and split3 into planes
    for (int e = tid; e < ROWS * 8; e += 256) {
        int rr = e >> 3, sl = e & 7;
        int g = g0 + rr;
        int ph = sl >> 2;
        int xr = (rr >> 1) & 3;           // CIN==32 swizzle
        int byte = rr * ROWB + ((((sl >> 1) ^ xr) << 4) | ((sl & 1) << 3));
        bool ok = (g >= 0 && g < Lin);
        int bx = 4 * rr + 2 * ph;
        s16x4 q0, q1, q2;
        #pragma unroll
        for (int j = 0; j < 4; ++j) {
            float v = 0.0f;
            if (ok) {
                int co = (sl & 3) * 4 + j;
                const float* wp = w0 + co * 7;
                float acc = 0.f;
                #pragma unroll
                for (int k = 0; k < 7; ++k)
                    acc = fmaf(wp[k], xs[bx + k], acc);
                v = elu(acc + b0[co]);
            }
            short a0, a1, a2;
            split3(v, a0, a1, a2);
            q0[j] = a0; q1[j] = a1; q2[j] = a2;
        }
        *(s16x4*)((char*)pl0 + byte) = q0;
        *(s16x4*)((char*)pl1 + byte) = q1;
        *(s16x4*)((char*)pl2 + byte) = q2;
    }
    __syncthreads();

    // ---- conv1 MFMA body (identical to conv_mfma3, OUTMODE=1) ----
    f32x4 acc[NTL][MT];
    #pragma unroll
    for (int n = 0; n < NTL; ++n)
        #pragma unroll
        for (int m = 0; m < MT; ++m) acc[n][m] = (f32x4){0.f, 0.f, 0.f, 0.f};

    int ncol = lane & 15, nq = lane >> 4;

    for (int k = 0; k < TAPS; ++k) {
        #pragma unroll
        for (int kc = 0; kc < KC; ++kc) {
            int colb = (kc * 32 + nq * 8) * 2;
            bf16x8 B0[NTL], B1[NTL], B2[NTL];
            #pragma unroll
            for (int ntl = 0; ntl < NTL; ++ntl) {
                int r  = S * ((wv * NTL + ntl) * 16 + ncol) + k;
                int xr = (r >> 1) & 3;
                int byte = r * ROWB + (colb ^ (xr << 4));
                B0[ntl] = *(const bf16x8*)((char*)pl0 + byte);
                B1[ntl] = *(const bf16x8*)((char*)pl1 + byte);
                B2[ntl] = *(const bf16x8*)((char*)pl2 + byte);
            }
            #pragma unroll
            for (int m = 0; m < MT; ++m) {
                size_t base = ((size_t)(m * KC + kc) * TAPS + k) * 3;
                bf16x8 a0 = *(const bf16x8*)(wfrag + (base + 0) * 512 + lane * 8);
                bf16x8 a1 = *(const bf16x8*)(wfrag + (base + 1) * 512 + lane * 8);
                bf16x8 a2 = *(const bf16x8*)(wfrag + (base + 2) * 512 + lane * 8);
                #pragma unroll
                for (int ntl = 0; ntl < NTL; ++ntl) {
                    f32x4 a = acc[ntl][m];
                    a = __builtin_amdgcn_mfma_f32_16x16x32_bf16(a0, B0[ntl], a, 0, 0, 0);
                    a = __builtin_amdgcn_mfma_f32_16x16x32_bf16(a1, B0[ntl], a, 0, 0, 0);
                    a = __builtin_amdgcn_mfma_f32_16x16x32_bf16(a2, B0[ntl], a, 0, 0, 0);
                    a = __builtin_amdgcn_mfma_f32_16x16x32_bf16(a0, B1[ntl], a, 0, 0, 0);
                    a = __builtin_amdgcn_mfma_f32_16x16x32_bf16(a1, B1[ntl], a, 0, 0, 0);
                    a = __builtin_amdgcn_mfma_f32_16x16x32_bf16(a0, B2[ntl], a, 0, 0, 0);
                    acc[ntl][m] = a;
                }
            }
        }
    }

    #pragma unroll
    for (int ntl = 0; ntl < NTL; ++ntl) {
        int n = t0 + (wv * NTL + ntl) * 16 + ncol;
        if (n < Lout) {
            #pragma unroll
            for (int m = 0; m < MT; ++m) {
                int co0 = m * 16 + nq * 4;
                float4 bb = *(const float4*)(bias + co0);
                float4 vv;
                vv.x = elu(acc[ntl][m][0] + bb.x);
                vv.y = elu(acc[ntl][m][1] + bb.y);
                vv.z = elu(acc[ntl][m][2] + bb.z);
                vv.w = elu(acc[ntl][m][3] + bb.w);
                *(float4*)(Hout + ((size_t)b * (Lout >> 1) + (n >> 1)) * (2 * COUT)
                           + (n & 1) * COUT + co0) = vv;
            }
        }
    }
}

// ---------------- weight prep: 3-level bf16 A-fragments ---------------------
template<int CIN, int COUT, int TAPS>
__global__ void wprep3_kernel(const float* __restrict__ w, short* __restrict__ frag)
{
    constexpr int KC = CIN / 32;
    int co = threadIdx.x;
    if (co >= COUT) return;
    int mt = co >> 4, nc = co & 15;
    for (int kc = 0; kc < KC; ++kc)
        for (int k = 0; k < TAPS; ++k)
            #pragma unroll
            for (int lh = 0; lh < 4; ++lh) {
                bf16x8 p0, p1, p2;
                #pragma unroll
                for (int j = 0; j < 8; ++j) {
                    int ci = kc * 32 + lh * 8 + j;
                    float f = w[(size_t)co * CIN * 7 + ci * 7 + k];
                    short a, bb, c; split3(f, a, bb, c);
                    p0[j] = a; p1[j] = bb; p2[j] = c;
                }
                size_t base = ((size_t)(mt * KC + kc) * TAPS + k) * 3;
                int off = (lh * 16 + nc) * 8;
                *(bf16x8*)(frag + (base + 0) * 512 + off) = p0;
                *(bf16x8*)(frag + (base + 1) * 512 + off) = p1;
                *(bf16x8*)(frag + (base + 2) * 512 + off) = p2;
            }
}

// phase-split packing (stride-2 K=7 -> stride-1 K=4 over doubled channels)
template<int CINH, int COUT>
__global__ void wprep3_ps_kernel(const float* __restrict__ w, short* __restrict__ frag)
{
    constexpr int CIN = 2 * CINH;
    constexpr int KC  = CIN / 32;
    int co = threadIdx.x;
    if (co >= COUT) return;
    int mt = co >> 4, nc = co & 15;
    for (int kc = 0; kc < KC; ++kc)
        for (int m = 0; m < 4; ++m)
            #pragma unroll
            for (int lh = 0; lh < 4; ++lh) {
                bf16x8 p0, p1, p2;
                #pragma unroll
                for (int j = 0; j < 8; ++j) {
                    int cp = kc * 32 + lh * 8 + j;
                    float f;
                    if (cp < CINH)  f = w[(size_t)co * CINH * 7 + cp * 7 + 2 * m];
                    else if (m < 3) f = w[(size_t)co * CINH * 7 + (cp - CINH) * 7 + 2 * m + 1];
                    else            f = 0.0f;
                    short a, bb, c; split3(f, a, bb, c);
                    p0[j] = a; p1[j] = bb; p2[j] = c;
                }
                size_t base = ((size_t)(mt * KC + kc) * 4 + m) * 3;
                int off = (lh * 16 + nc) * 8;
                *(bf16x8*)(frag + (base + 0) * 512 + off) = p0;
                *(bf16x8*)(frag + (base + 1) * 512 + off) = p1;
                *(bf16x8*)(frag + (base + 2) * 512 + off) = p2;
            }
}

// ---------------- conv via 6-term split3-bf16 MFMA, t-major fp32 I/O --------
template<int S, int CIN, int COUT, int NTL, int TAPS, int PAD, int OUTMODE>
__global__ __launch_bounds__(256) void conv_mfma3_kernel(
    const float* __restrict__ Hin, const short* __restrict__ wfrag,
    const float* __restrict__ bias, float* __restrict__ Hout,
    int Lin, int Lout)
{
    constexpr int KC   = CIN / 32;
    constexpr int MT   = COUT / 16;
    constexpr int NT   = NTL * 64;
    constexpr int ROWS = (NT - 1) * S + TAPS;
    constexpr int ROWB = CIN * 2;
    constexpr int NSL  = CIN / 4;
    __shared__ __align__(16) short pl0[ROWS * CIN];
    __shared__ __align__(16) short pl1[ROWS * CIN];
    __shared__ __align__(16) short pl2[ROWS * CIN];

    int nb = blockIdx.x, b = blockIdx.y;
    int t0 = nb * NT;
    int tid = threadIdx.x, lane = tid & 63, wv = tid >> 6;
    int g0 = t0 * S - PAD;

    const float* inb = Hin + (size_t)b * Lin * CIN;
    for (int e = tid; e < ROWS * NSL; e += 256) {
        int rr = e / NSL, sl = e % NSL;
        int g = g0 + rr;
        float4 v = {0.f, 0.f, 0.f, 0.f};
        if (g >= 0 && g < Lin)
            v = *(const float4*)(inb + (size_t)g * CIN + sl * 4);
        int xr = (CIN == 64) ? (rr & 7) : ((rr >> 1) & 3);
        int byte = rr * ROWB + ((((sl >> 1) ^ xr) << 4) | ((sl & 1) << 3));
        s16x4 q0, q1, q2;
        short a0, a1, a2;
        split3(v.x, a0, a1, a2); q0[0] = a0; q1[0] = a1; q2[0] = a2;
        split3(v.y, a0, a1, a2); q0[1] = a0; q1[1] = a1; q2[1] = a2;
        split3(v.z, a0, a1, a2); q0[2] = a0; q1[2] = a1; q2[2] = a2;
        split3(v.w, a0, a1, a2); q0[3] = a0; q1[3] = a1; q2[3] = a2;
        *(s16x4*)((char*)pl0 + byte) = q0;
        *(s16x4*)((char*)pl1 + byte) = q1;
        *(s16x4*)((char*)pl2 + byte) = q2;
    }
    __syncthreads();

    f32x4 acc[NTL][MT];
    #pragma unroll
    for (int n = 0; n < NTL; ++n)
        #pragma unroll
        for (int m = 0; m < MT; ++m) acc[n][m] = (f32x4){0.f, 0.f, 0.f, 0.f};

    int ncol = lane & 15, nq = lane >> 4;

    for (int k = 0; k < TAPS; ++k) {
        #pragma unroll
        for (int kc = 0; kc < KC; ++kc) {
            int colb = (kc * 32 + nq * 8) * 2;
            bf16x8 B0[NTL], B1[NTL], B2[NTL];
            #pragma unroll
            for (int ntl = 0; ntl < NTL; ++ntl) {
                int r  = S * ((wv * NTL + ntl) * 16 + ncol) + k;
                int xr = (CIN == 64) ? (r & 7) : ((r >> 1) & 3);
                int byte = r * ROWB + (colb ^ (xr << 4));
                B0[ntl] = *(const bf16x8*)((char*)pl0 + byte);
                B1[ntl] = *(const bf16x8*)((char*)pl1 + byte);
                B2[ntl] = *(const bf16x8*)((char*)pl2 + byte);
            }
            #pragma unroll
            for (int m = 0; m < MT; ++m) {
                size_t base = ((size_t)(m * KC + kc) * TAPS + k) * 3;
                bf16x8 a0 = *(const bf16x8*)(wfrag + (base + 0) * 512 + lane * 8);
                bf16x8 a1 = *(const bf16x8*)(wfrag + (base + 1) * 512 + lane * 8);
                bf16x8 a2 = *(const bf16x8*)(wfrag + (base + 2) * 512 + lane * 8);
                #pragma unroll
                for (int ntl = 0; ntl < NTL; ++ntl) {
                    f32x4 a = acc[ntl][m];
                    a = __builtin_amdgcn_mfma_f32_16x16x32_bf16(a0, B0[ntl], a, 0, 0, 0);
                    a = __builtin_amdgcn_mfma_f32_16x16x32_bf16(a1, B0[ntl], a, 0, 0, 0);
                    a = __builtin_amdgcn_mfma_f32_16x16x32_bf16(a2, B0[ntl], a, 0, 0, 0);
                    a = __builtin_amdgcn_mfma_f32_16x16x32_bf16(a0, B1[ntl], a, 0, 0, 0);
                    a = __builtin_amdgcn_mfma_f32_16x16x32_bf16(a1, B1[ntl], a, 0, 0, 0);
                    a = __builtin_amdgcn_mfma_f32_16x16x32_bf16(a0, B2[ntl], a, 0, 0, 0);
                    acc[ntl][m] = a;
                }
            }
        }
    }

    #pragma unroll
    for (int ntl = 0; ntl < NTL; ++ntl) {
        int n = t0 + (wv * NTL + ntl) * 16 + ncol;
        if (n < Lout) {
            #pragma unroll
            for (int m = 0; m < MT; ++m) {
                int co0 = m * 16 + nq * 4;
                float4 bb = *(const float4*)(bias + co0);
                float4 vv;
                vv.x = elu(acc[ntl][m][0] + bb.x);
                vv.y = elu(acc[ntl][m][1] + bb.y);
                vv.z = elu(acc[ntl][m][2] + bb.z);
                vv.w = elu(acc[ntl][m][3] + bb.w);
                if constexpr (OUTMODE == 0) {
                    *(float4*)(Hout + ((size_t)b * Lout + n) * COUT + co0) = vv;
                } else if constexpr (OUTMODE == 1) {
                    *(float4*)(Hout + ((size_t)b * (Lout >> 1) + (n >> 1)) * (2 * COUT)
                               + (n & 1) * COUT + co0) = vv;
                } else {
                    Hout[((size_t)b * COUT + co0 + 0) * Lout + n] = vv.x;
                    Hout[((size_t)b * COUT + co0 + 1) * Lout + n] = vv.y;
                    Hout[((size_t)b * COUT + co0 + 2) * Lout + n] = vv.z;
                    Hout[((size_t)b * COUT + co0 + 3) * Lout + n] = vv.w;
                }
            }
        }
    }
}

// ---------------- VQ prep: cc (fp32, +||c||^2) + (-2c) hi/lo bf16 B-frags ---
__global__ __launch_bounds__(256) void vq_prep_kernel(
    const float* __restrict__ cbs, float* __restrict__ cc, short* __restrict__ cbf)
{
    int c = blockIdx.x * 256 + threadIdx.x;   // 0..2047
    if (c >= 2048) return;
    int cb = c >> 10, nl = c & 1023;
    const float* row = cbs + (size_t)c * 64;
    float v[64];
    float s = 0.f;
    #pragma unroll
    for (int i = 0; i < 16; ++i) {
        float4 q = ((const float4*)row)[i];
        v[4*i+0] = q.x; v[4*i+1] = q.y; v[4*i+2] = q.z; v[4*i+3] = q.w;
        s += q.x*q.x + q.y*q.y + q.z*q.z + q.w*q.w;
    }
    cc[c] = s;
    int nt = nl >> 4, nc = nl & 15;
    #pragma unroll
    for (int kc = 0; kc < 2; ++kc)
        #pragma unroll
        for (int lh = 0; lh < 4; ++lh) {
            bf16x8 ph, pl;
            #pragma unroll
            for (int j = 0; j < 8; ++j) {
                float f = -2.0f * v[kc*32 + lh*8 + j];   // exact scaling
                short h = f2bf(f);
                ph[j] = h;
                pl[j] = f2bf(f - bf2f(h));
            }
            size_t base = ((((size_t)cb*64 + nt)*2 + kc)*2);
            *(bf16x8*)(cbf + ((base + 0)*64 + (lh*16 + nc)) * 8) = ph;
            *(bf16x8*)(cbf + ((base + 1)*64 + (lh*16 + nc)) * 8) = pl;
        }
}

__global__ void zero_cnt_kernel(int* cnt) {
    if (threadIdx.x == 0 && blockIdx.x == 0) { cnt[0] = 0; cnt[1] = 0; }
}

// ---------------- VQ main: MFMA scores, double-buffered 64-code chunks ------
#define VQ_MARGIN 0.04f

__global__ __launch_bounds__(256)
__attribute__((amdgpu_waves_per_eu(4, 4)))
void vq_mfma_kernel(
    const float* __restrict__ z, const short* __restrict__ cbf,
    const float* __restrict__ ccg, int* __restrict__ out,
    int* __restrict__ cnt, int* __restrict__ list0, int* __restrict__ list1)
{
    // 32 KB: z A-fragments during staging, then 2x16KB chunk double-buffer
    __shared__ __align__(16) short sbuf[16384];
    short* zf0 = sbuf;            // [8 mt][2 kc][64 lane][8] hi (16 KB)
    short* zf1 = sbuf + 8192;     // lo (16 KB)

    const int T = 2000;
    int mblk = blockIdx.x;
    int cb   = blockIdx.y;
    int b    = blockIdx.z;
    int t0   = mblk * 128;
    int tid  = threadIdx.x;
    int lane = tid & 63;
    int wv   = tid >> 6;
    int* list = cb ? list1 : list0;

    // ---- stage z -> hi/lo A-fragments (b128 rows, conflict-free) ----
    const float* zb = z + ((size_t)b*128 + (size_t)cb*64) * T;
    for (int e = tid; e < 128 * 8; e += 256) {
        int tl = e & 127;
        int d0 = (e >> 7) * 8;
        int tt = t0 + tl; if (tt > T - 1) tt = T - 1;
        bf16x8 hi, lo;
        #pragma unroll
        for (int jj = 0; jj < 8; ++jj) {
            float v = zb[(size_t)(d0 + jj) * T + tt];
            short h = f2bf(v);
            hi[jj] = h;
            lo[jj] = f2bf(v - bf2f(h));
        }
        int mt = tl >> 4, kc = d0 >> 5;
        int lw = ((d0 & 31) >> 3) * 16 + (tl & 15);
        int idx = ((mt*2 + kc)*64 + lw) * 8;
        *(bf16x8*)&zf0[idx] = hi;
        *(bf16x8*)&zf1[idx] = lo;
    }
    __syncthreads();

    bf16x8 ah[2][2], al[2][2];
    #pragma unroll
    for (int mtl = 0; mtl < 2; ++mtl)
        #pragma unroll
        for (int kc = 0; kc < 2; ++kc) {
            int idx = ((((wv*2+mtl)*2 + kc)*64) + lane)*8;
            ah[mtl][kc] = *(const bf16x8*)&zf0[idx];
            al[mtl][kc] = *(const bf16x8*)&zf1[idx];
        }
    __syncthreads();   // zf reads complete; sbuf is now the chunk double-buffer

    float best[2][4], second[2][4]; int bidx[2][4];
    #pragma unroll
    for (int m = 0; m < 2; ++m)
        #pragma unroll
        for (int j = 0; j < 4; ++j) { best[m][j] = 3.4e38f; second[m][j] = 3.4e38f; bidx[m][j] = 0; }

    const short* cbase = cbf + (size_t)cb * (64*2*2*64*8);
    const float* ccb   = ccg + cb * 1024;
    int c15 = lane & 15;

    {   // synchronous copy of chunk 0 into buf 0
        const float4* src = (const float4*)cbase;
        float4* dst = (float4*)sbuf;
        #pragma unroll
        for (int i = 0; i < 4; ++i) dst[tid + 256*i] = src[tid + 256*i];
    }
    __syncthreads();

    for (int ch = 0; ch < 16; ++ch) {
        short* cur = sbuf + (ch & 1) * 8192;
        short* nxt = sbuf + ((ch + 1) & 1) * 8192;
        float4 pre0, pre1, pre2, pre3;
        if (ch < 15) {   // issue-early: loads for next chunk
            const float4* src = (const float4*)(cbase + (size_t)(ch + 1) * 8192);
            pre0 = src[tid];       pre1 = src[tid + 256];
            pre2 = src[tid + 512]; pre3 = src[tid + 768];
        }

        #pragma unroll
        for (int ntl = 0; ntl < 4; ++ntl) {
            bf16x8 b0h = *(const bf16x8*)&cur[(((ntl*2 + 0)*2 + 0)*64 + lane)*8];
            bf16x8 b0l = *(const bf16x8*)&cur[(((ntl*2 + 0)*2 + 1)*64 + lane)*8];
            bf16x8 b1h = *(const bf16x8*)&cur[(((ntl*2 + 1)*2 + 0)*64 + lane)*8];
            bf16x8 b1l = *(const bf16x8*)&cur[(((ntl*2 + 1)*2 + 1)*64 + lane)*8];
            int  code = ch*64 + ntl*16 + c15;
            float ccv = ccb[code];                 // L1-resident 8KB table
            #pragma unroll
            for (int mtl = 0; mtl < 2; ++mtl) {
                f32x4 p = {ccv, ccv, ccv, ccv};
                __builtin_amdgcn_s_setprio(1);
                p = __builtin_amdgcn_mfma_f32_16x16x32_bf16(ah[mtl][0], b0h, p, 0, 0, 0);
                p = __builtin_amdgcn_mfma_f32_16x16x32_bf16(al[mtl][0], b0h, p, 0, 0, 0);
                p = __builtin_amdgcn_mfma_f32_16x16x32_bf16(ah[mtl][0], b0l, p, 0, 0, 0);
                p = __builtin_amdgcn_mfma_f32_16x16x32_bf16(ah[mtl][1], b1h, p, 0, 0, 0);
                p = __builtin_amdgcn_mfma_f32_16x16x32_bf16(al[mtl][1], b1h, p, 0, 0, 0);
                p = __builtin_amdgcn_mfma_f32_16x16x32_bf16(ah[mtl][1], b1l, p, 0, 0, 0);
                __builtin_amdgcn_s_setprio(0);
                #pragma unroll
                for (int j = 0; j < 4; ++j) {
                    float s = p[j];
                    bool lt = s < best[mtl][j];
                    second[mtl][j] = __builtin_amdgcn_fmed3f(best[mtl][j], s, second[mtl][j]);
                    best[mtl][j]   = fminf(best[mtl][j], s);
                    bidx[mtl][j]   = lt ? code : bidx[mtl][j];
                }
            }
        }

        if (ch < 15) {   // write-late into the other buffer
            float4* dst = (float4*)nxt;
            dst[tid]       = pre0;  dst[tid + 256] = pre1;
            dst[tid + 512] = pre2;  dst[tid + 768] = pre3;
        }
        __syncthreads();  // writes to nxt visible; reads of cur done
    }

    #pragma unroll
    for (int m = 0; m < 2; ++m)
        #pragma unroll
        for (int j = 0; j < 4; ++j) {
            float bv = best[m][j], sv = second[m][j]; int bi = bidx[m][j];
            #pragma unroll
            for (int d = 1; d < 16; d <<= 1) {
                float ob = __shfl_xor(bv, d, 64);
                float os = __shfl_xor(sv, d, 64);
                int   oi = __shfl_xor(bi, d, 64);
                float loser = fmaxf(bv, ob);
                sv = fminf(fminf(sv, os), loser);
                bool sw = ob < bv;
                bv = fminf(bv, ob);
                bi = sw ? oi : bi;
            }
            if ((lane & 15) == 0) {
                int t = t0 + (wv*2 + m)*16 + (lane >> 4)*4 + j;
                if (t < T) {
                    out[((size_t)cb*64 + b)*T + t] = bi;
                    if (sv - bv < VQ_MARGIN) {
                        int pos = atomicAdd(&cnt[cb], 1);
                        list[pos] = (b << 11) | t;
                    }
                }
            }
        }
}

// ---------------- VQ rescore: 4 same-cb flags/iter share cb+w streams -------
__global__ __launch_bounds__(256) void vq_rescore_kernel(
    const float* __restrict__ H3, const float* __restrict__ wq,
    const float* __restrict__ bq, const float* __restrict__ cbs,
    const float* __restrict__ ccg, const int* __restrict__ cnt,
    const int* __restrict__ list0, const int* __restrict__ list1,
    int* __restrict__ out)
{
    const int T = 2000;
    __shared__ float hp[4][4][448];     // 28 KB
    __shared__ float zsh[4][4][64];     // 4 KB
    int tid = threadIdx.x, lane = tid & 63, wv = tid >> 6;
    int cb = blockIdx.y;
    const int* list = cb ? list1 : list0;
    int count = cnt[cb];
    int gw = blockIdx.x * 4 + wv, nw = gridDim.x * 4;

    const float* cbase = cbs + (size_t)cb * 1024 * 64;
    const float* ccb   = ccg + cb * 1024;
    int d = cb * 64 + lane;
    const float4* wp = (const float4*)(wq + (size_t)d * 448);
    float bqd = bq[d];

    for (int i0 = gw * 4; i0 < count; i0 += nw * 4) {
        int bf_[4], tf_[4];
        #pragma unroll
        for (int f = 0; f < 4; ++f) {
            int idx = i0 + f; if (idx > count - 1) idx = count - 1;
            int e = list[idx];
            bf_[f] = e >> 11; tf_[f] = e & 2047;
        }

        #pragma unroll
        for (int f = 0; f < 4; ++f) {
            size_t base = (size_t)bf_[f] * T * 64;
            #pragma unroll
            for (int kk = 0; kk < 7; ++kk) {
                int a = tf_[f] - 6 + kk;
                hp[wv][f][lane * 7 + kk] = (a >= 0) ? H3[base + (size_t)a * 64 + lane] : 0.0f;
            }
        }

        float pa[4][4];
        #pragma unroll
        for (int f = 0; f < 4; ++f)
            #pragma unroll
            for (int j = 0; j < 4; ++j) pa[f][j] = 0.f;
        #pragma unroll 4
        for (int q = 0; q < 112; ++q) {
            float4 w4 = wp[q];
            #pragma unroll
            for (int f = 0; f < 4; ++f) {
                float4 h = *(const float4*)&hp[wv][f][4 * q];
                pa[f][0] = fmaf(w4.x, h.x, pa[f][0]);
                pa[f][1] = fmaf(w4.y, h.y, pa[f][1]);
                pa[f][2] = fmaf(w4.z, h.z, pa[f][2]);
                pa[f][3] = fmaf(w4.w, h.w, pa[f][3]);
            }
        }
        #pragma unroll
        for (int f = 0; f < 4; ++f) {
            float zv = (pa[f][0] + pa[f][1]) + (pa[f][2] + pa[f][3]) + bqd;
            zsh[wv][f][lane] = zv > 0.f ? zv : expm1f(zv);
        }

        float bv[4]; int bi[4];
        #pragma unroll
        for (int f = 0; f < 4; ++f) { bv[f] = 3.4e38f; bi[f] = 0; }
        for (int ii = 0; ii < 16; ++ii) {
            int code = ii * 64 + lane;
            const float4* cp = (const float4*)(cbase + (size_t)code * 64);
            float dd[4][4];
            #pragma unroll
            for (int f = 0; f < 4; ++f)
                #pragma unroll
                for (int j = 0; j < 4; ++j) dd[f][j] = 0.f;
            #pragma unroll
            for (int q = 0; q < 16; ++q) {
                float4 cv = cp[q];
                #pragma unroll
                for (int f = 0; f < 4; ++f) {
                    float4 za = *(const float4*)&zsh[wv][f][4 * q];   // uniform broadcast
                    dd[f][0] = fmaf(za.x, cv.x, dd[f][0]);
                    dd[f][1] = fmaf(za.y, cv.y, dd[f][1]);
                    dd[f][2] = fmaf(za.z, cv.z, dd[f][2]);
                    dd[f][3] = fmaf(za.w, cv.w, dd[f][3]);
                }
            }
            float cc0 = ccb[code];
            #pragma unroll
            for (int f = 0; f < 4; ++f) {
                float s = fmaf(-2.0f, (dd[f][0] + dd[f][1]) + (dd[f][2] + dd[f][3]), cc0);
                if (s < bv[f]) { bv[f] = s; bi[f] = code; }
            }
        }
        #pragma unroll
        for (int ddp = 1; ddp < 64; ddp <<= 1) {
            #pragma unroll
            for (int f = 0; f < 4; ++f) {
                float ov = __shfl_xor(bv[f], ddp, 64);
                int   oi = __shfl_xor(bi[f], ddp, 64);
                if (ov < bv[f] || (ov == bv[f] && oi < bi[f])) { bv[f] = ov; bi[f] = oi; }
            }
        }
        if (lane == 0) {
            #pragma unroll
            for (int f = 0; f < 4; ++f)
                out[((size_t)cb * 64 + bf_[f]) * T + tf_[f]] = bi[f];
        }
    }
}

extern "C" void kernel_launch(void* const* d_in, const int* in_sizes, int n_in,
                              void* d_out, int out_size, void* d_ws, size_t ws_size,
                              hipStream_t stream)
{
    const float* x   = (const float*)d_in[0];
    const float* w0  = (const float*)d_in[1];
    const float* b0  = (const float*)d_in[2];
    const float* w1  = (const float*)d_in[3];
    const float* b1  = (const float*)d_in[4];
    const float* w2  = (const float*)d_in[5];
    const float* b2  = (const float*)d_in[6];
    const float* w3  = (const float*)d_in[7];
    const float* b3  = (const float*)d_in[8];
    const float* wq  = (const float*)d_in[9];
    const float* bq  = (const float*)d_in[10];
    const float* cbs = (const float*)d_in[11];
    int* out = (int*)d_out;

    // two 98,304,000-byte regions (proven footprint)
    char* r1 = (char*)d_ws;
    char* r2 = r1 + 98304000;
    float* H1 = (float*)r2;               // [64][6000][64]  (phase-split)
    float* H2 = (float*)r1;               // [64][6000][64]
    float* H3 = (float*)r2;               // [64][2000][64]  (over dead H1)
    float* z  = (float*)(r2 + 32768000);  // [64][128][2000] fp32

    // weight fragments in d_out (dead until vq_mfma rewrites it)
    short* wf1 = (short*)d_out;           // 12288 shorts
    short* wf2 = wf1 + 12288;             // 49152
    short* wf3 = wf1 + 61440;             // 86016
    short* wf4 = wf1 + 147456;            // 172032 -> ends at 319488 shorts

    // VQ prep data in r1 (free after conv3 consumes H2)
    short* cbf   = (short*)r1;
    float* cc    = (float*)(r1 + 524288);
    int*   cnt   = (int*)(r1 + 540000);
    int*   list0 = (int*)(r1 + 1000000);
    int*   list1 = (int*)(r1 + 2100000);

    // weight prep (reads inputs only)
    wprep3_ps_kernel<16, 32><<<1, 32, 0, stream>>>(w1, wf1);
    wprep3_ps_kernel<32, 64><<<1, 64, 0, stream>>>(w2, wf2);
    wprep3_kernel<64, 64, 7><<<1, 64, 0, stream>>>(w3, wf3);
    wprep3_kernel<64, 128, 7><<<1, 128, 0, stream>>>(wq, wf4);

    // fused conv0+conv1: x -> H1 (phase-split), H0 recomputed in-kernel
    conv01_kernel<<<dim3(94, 64), 256, 0, stream>>>(x, w0, b0, wf1, b1, H1);
    // conv2: H1 -> H2, stride-1 K=4 over 64ch, t-major out
    conv_mfma3_kernel<1, 64, 64, 2, 4, 3, 0><<<dim3(47, 64), 256, 0, stream>>>(
        H1, wf2, b2, H2, 6000, 6000);
    // conv3: H2 -> H3, stride 3, K=7, t-major out
    conv_mfma3_kernel<3, 64, 64, 1, 7, 6, 0><<<dim3(32, 64), 256, 0, stream>>>(
        H2, wf3, b3, H3, 6000, 2000);

    // VQ prep into r1 (H2 now dead)
    vq_prep_kernel<<<8, 256, 0, stream>>>(cbs, cc, cbf);
    zero_cnt_kernel<<<1, 64, 0, stream>>>(cnt);

    // conv4: H3 -> z (fp32 [co][t]), stride 1, K=7
    conv_mfma3_kernel<1, 64, 128, 2, 7, 6, 2><<<dim3(16, 64), 256, 0, stream>>>(
        H3, wf4, bq, z, 2000, 2000);

    // VQ: MFMA scores + per-cb flag lists, then 4-way shared exact rescore
    vq_mfma_kernel<<<dim3(16, 2, 64), 256, 0, stream>>>(z, cbf, cc, out, cnt, list0, list1);
    vq_rescore_kernel<<<dim3(512, 2), 256, 0, stream>>>(H3, wq, bq, cbs, cc, cnt, list0, list1, out);
}